// Round 1
// baseline (5223.763 us; speedup 1.0000x reference)
//
#include <hip/hip_runtime.h>

#define HDIM 8192
#define FK 15

// ---------------------------------------------------------------------------
// permute blur weight: Wp[(f*C+c)*O + o] = W[o*(C*F) + c*F + f]
__global__ void k_perm_blur_w(const float* __restrict__ W, float* __restrict__ Wp,
                              int O, int C) {
    int e = blockIdx.x * 256 + threadIdx.x;
    int total = O * C * FK;
    if (e >= total) return;
    int o = e % O;
    int rest = e / O;
    int c = rest % C;
    int f = rest / C;
    Wp[e] = W[(size_t)o * (C * FK) + c * FK + f];
}

// permute corr-out weight: Wp[o2*480 + f*32 + o] = W[o2*480 + o*15 + f]
__global__ void k_perm_corr_w(const float* __restrict__ W, float* __restrict__ Wp,
                              int O2) {
    int e = blockIdx.x * 256 + threadIdx.x;
    if (e >= O2 * 480) return;
    int j = e % 480;
    int o2 = e / 480;
    int o = j & 31;
    int f = j >> 5;
    Wp[e] = W[(size_t)o2 * 480 + o * 15 + f];
}

// copy 4 el rows (c-major (4,N)) into catT cols 0..3
__global__ void k_copy_el(const float* __restrict__ el, float* __restrict__ catT,
                          int N, int ld) {
    int n = blockIdx.x * 256 + threadIdx.x;
    if (n >= N) return;
#pragma unroll
    for (int j = 0; j < 4; ++j) catT[(size_t)n * ld + j] = el[(size_t)j * N + n];
}

// ---------------------------------------------------------------------------
// embed: X (32,N) c-major -> outT[n*ld + coff + o] = lrelu(W(O,32)@X + b)
__global__ __launch_bounds__(256) void k_embed(const float* __restrict__ X,
                                               const float* __restrict__ W,
                                               const float* __restrict__ b,
                                               float* __restrict__ outT,
                                               int N, int O, int ld, int coff) {
    __shared__ float Xs[32][65];
    int tid = threadIdx.x;
    int n0 = blockIdx.x * 64;
    for (int e = tid; e < 32 * 64; e += 256) {
        int nn = e & 63, c = e >> 6;
        Xs[c][nn] = X[(size_t)c * N + n0 + nn];
    }
    __syncthreads();
    int ol = tid & 63, nl = tid >> 6;
    for (int o0 = 0; o0 < O; o0 += 64) {
        int o = o0 + ol;
        float wv[32];
#pragma unroll
        for (int c = 0; c < 32; ++c) wv[c] = W[o * 32 + c];
        float bv = b[o];
        for (int nn = nl; nn < 64; nn += 4) {
            float acc = bv;
#pragma unroll
            for (int c = 0; c < 32; ++c) acc += wv[c] * Xs[c][nn];
            acc = acc >= 0.f ? acc : 0.1f * acc;
            outT[(size_t)(n0 + nn) * ld + coff + o] = acc;
        }
    }
}

// ---------------------------------------------------------------------------
// blur GEMM with fused neighbor gather:
//   outT[h][o] = act( sum_{f,c} Wp[(f*C+c)*O+o] * catT[nbrs[f][h]][c] + bias[o] )
__global__ __launch_bounds__(256) void k_blur_gemm(const float* __restrict__ catT,
                                                   const int* __restrict__ nbrs,
                                                   const float* __restrict__ Wp,
                                                   const float* __restrict__ bias,
                                                   float* __restrict__ outT,
                                                   int C, int O, int H, int act) {
    __shared__ int idx_s[FK * 64];
    __shared__ float As[32][64];
    __shared__ float Bs[32][65];
    int tid = threadIdx.x;
    int h0 = blockIdx.x * 64;
    int o0 = blockIdx.y * 64;
    for (int e = tid; e < FK * 64; e += 256) {
        int f = e / 64, hh = e & 63;
        idx_s[e] = nbrs[(size_t)f * H + h0 + hh];
    }
    __syncthreads();
    float acc[4][4] = {};
    int tx = tid & 15, ty = tid >> 4;  // tx->o, ty->h
    for (int f = 0; f < FK; ++f) {
        for (int c0 = 0; c0 < C; c0 += 32) {
            int kc = (C - c0) < 32 ? (C - c0) : 32;
            for (int e = tid; e < kc * 64; e += 256) {
                int o = e & 63, kk = e >> 6;
                As[kk][o] = Wp[(size_t)(f * C + c0 + kk) * O + o0 + o];
            }
            if (kc == 32) {
                for (int e = tid; e < 2048; e += 256) {
                    int kk = e & 31, hh = e >> 5;
                    Bs[kk][hh] = catT[(size_t)idx_s[f * 64 + hh] * C + c0 + kk];
                }
            } else {
                for (int e = tid; e < kc * 64; e += 256) {
                    int kk = e % kc, hh = e / kc;
                    Bs[kk][hh] = catT[(size_t)idx_s[f * 64 + hh] * C + c0 + kk];
                }
            }
            __syncthreads();
            for (int kk = 0; kk < kc; ++kk) {
                float a[4], bb[4];
#pragma unroll
                for (int j = 0; j < 4; ++j) a[j] = As[kk][tx + 16 * j];
#pragma unroll
                for (int i = 0; i < 4; ++i) bb[i] = Bs[kk][ty + 16 * i];
#pragma unroll
                for (int i = 0; i < 4; ++i)
#pragma unroll
                    for (int j = 0; j < 4; ++j)
                        acc[i][j] = fmaf(bb[i], a[j], acc[i][j]);
            }
            __syncthreads();
        }
    }
#pragma unroll
    for (int i = 0; i < 4; ++i)
#pragma unroll
        for (int j = 0; j < 4; ++j) {
            int o = o0 + tx + 16 * j;
            int h = h0 + ty + 16 * i;
            float v = acc[i][j] + bias[o];
            if (act) v = v >= 0.f ? v : 0.1f * v;
            outT[(size_t)h * O + o] = v;
        }
}

// ---------------------------------------------------------------------------
// dense GEMM: outT (N,O) = act( Xt (N,C) @ W(O,C)^T + b )
__global__ __launch_bounds__(256) void k_gemm_tn(const float* __restrict__ Xt,
                                                 const float* __restrict__ W,
                                                 const float* __restrict__ bias,
                                                 float* __restrict__ outT,
                                                 int N, int C, int O, int act) {
    __shared__ float Xs[64][33];
    __shared__ float Ws[64][33];
    int tid = threadIdx.x;
    int n0 = blockIdx.x * 64;
    int o0 = blockIdx.y * 64;
    float acc[4][4] = {};
    int tx = tid & 15, ty = tid >> 4;  // tx->o, ty->n
    for (int c0 = 0; c0 < C; c0 += 32) {
        for (int e = tid; e < 2048; e += 256) {
            int cc = e & 31, r = e >> 5;
            Xs[r][cc] = Xt[(size_t)(n0 + r) * C + c0 + cc];
            Ws[r][cc] = W[(size_t)(o0 + r) * C + c0 + cc];
        }
        __syncthreads();
#pragma unroll 8
        for (int kk = 0; kk < 32; ++kk) {
            float a[4], bb[4];
#pragma unroll
            for (int j = 0; j < 4; ++j) a[j] = Ws[tx + 16 * j][kk];
#pragma unroll
            for (int i = 0; i < 4; ++i) bb[i] = Xs[ty + 16 * i][kk];
#pragma unroll
            for (int i = 0; i < 4; ++i)
#pragma unroll
                for (int j = 0; j < 4; ++j)
                    acc[i][j] = fmaf(bb[i], a[j], acc[i][j]);
        }
        __syncthreads();
    }
#pragma unroll
    for (int i = 0; i < 4; ++i)
#pragma unroll
        for (int j = 0; j < 4; ++j) {
            int o = o0 + tx + 16 * j;
            int n = n0 + ty + 16 * i;
            float v = acc[i][j] + bias[o];
            if (act) v = v >= 0.f ? v : 0.1f * v;
            outT[(size_t)n * O + o] = v;
        }
}

// ---------------------------------------------------------------------------
// slice: outT[n*ld + coff + c] = sum_j latT[off[j][n]][c] * bary[j][n]
__global__ void k_slice(const float* __restrict__ latT, const float* __restrict__ bary,
                        const int* __restrict__ off, float* __restrict__ outT,
                        int N, int C, int ld, int coff) {
    int cl = threadIdx.x & 63, r = threadIdx.x >> 6;
    int n = blockIdx.x * 4 + r;
    int c = blockIdx.y * 64 + cl;
    float s = 0.f;
#pragma unroll
    for (int j = 0; j < 4; ++j) {
        int o = off[(size_t)j * N + n];
        float w = bary[(size_t)j * N + n];
        s += latT[(size_t)o * C + c] * w;
    }
    outT[(size_t)n * ld + coff + c] = s;
}

// splat: latT[off[j][n]][c] += featT[n][c] * bary[j][n]   (latT pre-zeroed)
__global__ void k_splat(const float* __restrict__ featT, const float* __restrict__ bary,
                        const int* __restrict__ off, float* __restrict__ latT,
                        int N, int C) {
    int cl = threadIdx.x & 63, r = threadIdx.x >> 6;
    int n = blockIdx.x * 4 + r;
    int c = blockIdx.y * 64 + cl;
    float v = featT[(size_t)n * C + c];
#pragma unroll
    for (int j = 0; j < 4; ++j) {
        int o = off[(size_t)j * N + n];
        float w = bary[(size_t)j * N + n];
        atomicAdd(&latT[(size_t)o * C + c], v * w);
    }
}

// ---------------------------------------------------------------------------
// fused correlation MLP: per position (f,h):
//   x[c]      = L1T[i1][c] * f2T[i2][c]            c < C1
//   x[C1+cp]  = P1T[i1][cp]                        cp < C2 (optional)
//   a0 = lrelu(W0 @ x + b0); h1 = lrelu(W1 @ a0 + b1)   (both 32-wide)
//   h1T[h][f*32 + o] = h1[o]
__global__ __launch_bounds__(256) void k_corr_mlp(const float* __restrict__ L1T,
                                                  const float* __restrict__ f2T,
                                                  const float* __restrict__ P1T,
                                                  const int* __restrict__ idx1,
                                                  const int* __restrict__ idx2,
                                                  const float* __restrict__ W0,
                                                  const float* __restrict__ b0,
                                                  const float* __restrict__ W1,
                                                  const float* __restrict__ b1,
                                                  float* __restrict__ h1T,
                                                  int H, int C1, int C2) {
    __shared__ float Ws[32][64];
    __shared__ float W1s[32][32];
    __shared__ float b0s[32], b1s[32];
    int tid = threadIdx.x;
    for (int e = tid; e < 1024; e += 256) W1s[e >> 5][e & 31] = W1[e];
    if (tid < 32) { b0s[tid] = b0[tid]; b1s[tid] = b1[tid]; }
    __syncthreads();
    int p = blockIdx.x * 256 + tid;
    int f = p >> 13;            // H == 8192
    int h = p & (HDIM - 1);
    int i1 = idx1[(size_t)f * H + h];
    int i2 = idx2[(size_t)f * H + h];
    float acc[32];
#pragma unroll
    for (int o = 0; o < 32; ++o) acc[o] = b0s[o];
    int K = C1 + C2;
    for (int c0 = 0; c0 < K; c0 += 64) {
        __syncthreads();
        for (int e = tid; e < 2048; e += 256) {
            int cc = e & 63, o = e >> 6;
            Ws[o][cc] = W0[(size_t)o * K + c0 + cc];
        }
        __syncthreads();
        if (c0 < C1) {
            const float4* a4 = (const float4*)(L1T + (size_t)i1 * C1 + c0);
            const float4* b4 = (const float4*)(f2T + (size_t)i2 * C1 + c0);
#pragma unroll 4
            for (int q = 0; q < 16; ++q) {
                float4 av = a4[q], bv = b4[q];
                float xs[4] = {av.x * bv.x, av.y * bv.y, av.z * bv.z, av.w * bv.w};
#pragma unroll
                for (int u = 0; u < 4; ++u) {
                    float xv = xs[u];
                    int cc = q * 4 + u;
#pragma unroll
                    for (int o = 0; o < 32; ++o) acc[o] = fmaf(Ws[o][cc], xv, acc[o]);
                }
            }
        } else {
            const float4* a4 = (const float4*)(P1T + (size_t)i1 * C2 + (c0 - C1));
#pragma unroll 4
            for (int q = 0; q < 16; ++q) {
                float4 av = a4[q];
                float xs[4] = {av.x, av.y, av.z, av.w};
#pragma unroll
                for (int u = 0; u < 4; ++u) {
                    float xv = xs[u];
                    int cc = q * 4 + u;
#pragma unroll
                    for (int o = 0; o < 32; ++o) acc[o] = fmaf(Ws[o][cc], xv, acc[o]);
                }
            }
        }
    }
    float a0[32];
#pragma unroll
    for (int o = 0; o < 32; ++o) {
        float x = acc[o];
        a0[o] = x >= 0.f ? x : 0.1f * x;
    }
    float h1v[32];
#pragma unroll
    for (int o = 0; o < 32; ++o) {
        float s = b1s[o];
#pragma unroll
        for (int i = 0; i < 32; ++i) s = fmaf(W1s[o][i], a0[i], s);
        h1v[o] = s >= 0.f ? s : 0.1f * s;
    }
    float4* dst = (float4*)(h1T + (size_t)h * 480 + f * 32);
#pragma unroll
    for (int q = 0; q < 8; ++q)
        dst[q] = make_float4(h1v[4 * q], h1v[4 * q + 1], h1v[4 * q + 2], h1v[4 * q + 3]);
}

// ---------------------------------------------------------------------------
// final 256 -> 3 head, writes (3, N) c-major
__global__ void k_final(const float* __restrict__ r2T, const float* __restrict__ W,
                        const float* __restrict__ b, float* __restrict__ out, int N) {
    int n = blockIdx.x * 256 + threadIdx.x;
    if (n >= N) return;
    float s0 = b[0], s1 = b[1], s2 = b[2];
    const float4* x4 = (const float4*)(r2T + (size_t)n * 256);
    for (int q = 0; q < 64; ++q) {
        float4 v = x4[q];
        float xs[4] = {v.x, v.y, v.z, v.w};
#pragma unroll
        for (int u = 0; u < 4; ++u) {
            int c = 4 * q + u;
            s0 = fmaf(W[c], xs[u], s0);
            s1 = fmaf(W[256 + c], xs[u], s1);
            s2 = fmaf(W[512 + c], xs[u], s2);
        }
    }
    out[n] = s0;
    out[(size_t)N + n] = s1;
    out[(size_t)2 * N + n] = s2;
}

// ---------------------------------------------------------------------------
extern "C" void kernel_launch(void* const* d_in, const int* in_sizes, int n_in,
                              void* d_out, int out_size, void* d_ws, size_t ws_size,
                              hipStream_t stream) {
    const int N = HDIM;
    auto F32 = [&](int i) { return (const float*)d_in[i]; };
    auto I32 = [&](int i) { return (const int*)d_in[i]; };

    char* base = (char*)d_ws;
    size_t off = 0;
    auto alloc = [&](size_t elems) -> float* {
        float* r = (float*)(base + off);
        off += ((elems * 4 + 255) / 256) * 256;
        return r;
    };
    float* wp_up2 = alloc((size_t)256 * 132 * FK);
    float* wp_up1 = alloc((size_t)512 * 516 * FK);
    float* wp_c2o = alloc((size_t)256 * 480);
    float* wp_c1o = alloc((size_t)512 * 480);
    float* catT2 = alloc((size_t)N * 132);
    float* cat1_0 = alloc((size_t)N * 516);
    float* cat1_1 = alloc((size_t)N * 516);
    float* t512a = alloc((size_t)N * 512);
    float* t512b = alloc((size_t)N * 512);
    float* pcl01 = alloc((size_t)N * 512);   // later corr1
    float* pcl11 = alloc((size_t)N * 512);
    float* pclA = alloc((size_t)N * 256);    // pcl0_2 ; SL512 = pclA..pclB
    float* pclB = alloc((size_t)N * 256);    // pcl1_2
    float* SL256 = alloc((size_t)N * 256);   // corr2 splat L ; later SP256
    float* corr2T = alloc((size_t)N * 256);
    float* h1T = alloc((size_t)N * 480);
    float* SL512 = pclA;   // aliases pclA+pclB (both dead by stage D)
    float* SP256 = SL256;  // dead by stage D
    float* t256a = t512a;  // front 8 MB aliases
    float* t256b = t512b;
    (void)ws_size; (void)in_sizes; (void)n_in; (void)out_size;

    // --- weight permutes (recomputed every launch; deterministic) ---
    k_perm_blur_w<<<(256 * 132 * FK + 255) / 256, 256, 0, stream>>>(F32(32), wp_up2, 256, 132);
    k_perm_blur_w<<<(512 * 516 * FK + 255) / 256, 256, 0, stream>>>(F32(36), wp_up1, 512, 516);
    k_perm_corr_w<<<(256 * 480 + 255) / 256, 256, 0, stream>>>(F32(44), wp_c2o, 256);
    k_perm_corr_w<<<(512 * 480 + 255) / 256, 256, 0, stream>>>(F32(52), wp_c1o, 512);

    // --- Stage A: level-2 embed + blur + slices (per stream) ---
    auto stageA = [&](const float* el, const float* feat, const int* nbrs,
                      const float* baryA, const int* offA, float* pcl2,
                      const float* baryB, const int* offB, float* cat1dst) {
        k_copy_el<<<32, 256, 0, stream>>>(el, catT2, N, 132);
        k_embed<<<128, 256, 0, stream>>>(feat, F32(28), F32(29), catT2, N, 128, 132, 4);
        k_blur_gemm<<<dim3(128, 4), 256, 0, stream>>>(catT2, nbrs, wp_up2, F32(33),
                                                      t256a, 132, 256, N, 1);
        k_gemm_tn<<<dim3(128, 4), 256, 0, stream>>>(t256a, F32(34), F32(35), t256b,
                                                    N, 256, 256, 0);
        k_slice<<<dim3(2048, 4), 256, 0, stream>>>(t256b, baryA, offA, pcl2, N, 256, 256, 0);
        k_slice<<<dim3(2048, 4), 256, 0, stream>>>(t256b, baryB, offB, cat1dst, N, 256, 516, 4);
    };
    stageA(F32(6), F32(1), I32(20), F32(10), I32(15), pclA, F32(12), I32(17), cat1_0);
    stageA(F32(7), F32(4), I32(21), F32(11), I32(16), pclB, F32(13), I32(18), cat1_1);

    // --- Stage B: corr2 ---
    hipMemsetAsync(SL256, 0, (size_t)N * 256 * 4, stream);
    k_splat<<<dim3(2048, 4), 256, 0, stream>>>(pclA, F32(10), I32(15), SL256, N, 256);
    k_corr_mlp<<<FK * HDIM / 256, 256, 0, stream>>>(SL256, pclB, (const float*)nullptr,
                                                    I32(24), I32(25), F32(40), F32(41),
                                                    F32(42), F32(43), h1T, N, 256, 0);
    k_gemm_tn<<<dim3(128, 4), 256, 0, stream>>>(h1T, wp_c2o, F32(45), t256a, N, 480, 256, 1);
    k_gemm_tn<<<dim3(128, 4), 256, 0, stream>>>(t256a, F32(46), F32(47), t256b, N, 256, 256, 0);
    k_slice<<<dim3(2048, 4), 256, 0, stream>>>(t256b, F32(12), I32(17), corr2T, N, 256, 256, 0);

    // --- Stage C: level-1 embed + blur + slices (per stream) ---
    auto stageC = [&](const float* el, const float* feat, const int* nbrs, float* cat1,
                      const float* baryO, const int* offO, float* pclOut) {
        k_copy_el<<<32, 256, 0, stream>>>(el, cat1, N, 516);
        k_embed<<<128, 256, 0, stream>>>(feat, F32(30), F32(31), cat1, N, 256, 516, 260);
        k_blur_gemm<<<dim3(128, 8), 256, 0, stream>>>(cat1, nbrs, wp_up1, F32(37),
                                                      t512a, 516, 512, N, 1);
        k_gemm_tn<<<dim3(128, 8), 256, 0, stream>>>(t512a, F32(38), F32(39), t512b,
                                                    N, 512, 512, 0);
        k_slice<<<dim3(2048, 8), 256, 0, stream>>>(t512b, baryO, offO, pclOut, N, 512, 512, 0);
    };
    stageC(F32(8), F32(0), I32(22), cat1_0, F32(12), I32(17), pcl01);
    stageC(F32(9), F32(3), I32(23), cat1_1, F32(13), I32(18), pcl11);

    // --- Stage D: corr1 ---
    hipMemsetAsync(SL512, 0, (size_t)N * 512 * 4, stream);
    k_splat<<<dim3(2048, 8), 256, 0, stream>>>(pcl01, F32(12), I32(17), SL512, N, 512);
    hipMemsetAsync(SP256, 0, (size_t)N * 256 * 4, stream);
    k_splat<<<dim3(2048, 4), 256, 0, stream>>>(corr2T, F32(12), I32(17), SP256, N, 256);
    k_corr_mlp<<<FK * HDIM / 256, 256, 0, stream>>>(SL512, pcl11, SP256,
                                                    I32(26), I32(27), F32(48), F32(49),
                                                    F32(50), F32(51), h1T, N, 512, 256);
    k_gemm_tn<<<dim3(128, 8), 256, 0, stream>>>(h1T, wp_c1o, F32(53), t512a, N, 480, 512, 1);
    k_gemm_tn<<<dim3(128, 8), 256, 0, stream>>>(t512a, F32(54), F32(55), t512b, N, 512, 512, 0);
    k_slice<<<dim3(2048, 8), 256, 0, stream>>>(t512b, F32(14), I32(19), pcl01, N, 512, 512, 0);

    // --- Stage E: head ---
    k_gemm_tn<<<dim3(128, 8), 256, 0, stream>>>(pcl01, F32(56), F32(57), t512a, N, 512, 512, 1);
    k_gemm_tn<<<dim3(128, 4), 256, 0, stream>>>(t512a, F32(58), F32(59), t512b, N, 512, 256, 1);
    k_final<<<32, 256, 0, stream>>>(t512b, F32(60), F32(61), (float*)d_out, N);
}

// Round 2
// 1514.650 us; speedup vs baseline: 3.4488x; 3.4488x over previous
//
#include <hip/hip_runtime.h>
#include <hip/hip_bf16.h>

#define HDIM 8192
#define FK 15

typedef __attribute__((ext_vector_type(8))) short bf16x8;
typedef __attribute__((ext_vector_type(4))) float f32x4;

// ---------------------------------------------------------------------------
// pack weights to bf16 in MFMA b-fragment order:
//   P[(kt*(O/16)+ot)*512 + lane*8 + j] = Wsrc[o = ot*16+(lane&15)][k' = kt*32+(lane>>4)*8+j]
// mode 0: dense  Wsrc[o][k'] = W[o*C + k']          (Cp == C)
// mode 1: blur   f=k'/Cp, c=k'%Cp; = c<C ? W[o*C*Fk + c*Fk + f] : 0
// mode 2: corr   f=k'/32, oo=k'%32; = W[o*480 + oo*15 + f]
__global__ void k_pack(const float* __restrict__ W, __hip_bfloat16* __restrict__ P,
                       int O, int C, int Cp, int Fk, int mode) {
    int e = blockIdx.x * 256 + threadIdx.x;
    int total = Fk * Cp * O;
    if (e >= total) return;
    int j = e & 7;
    int lane = (e >> 3) & 63;
    int tile = e >> 9;
    int OT = O >> 4;
    int ot = tile % OT, kt = tile / OT;
    int o = ot * 16 + (lane & 15);
    int kk = kt * 32 + (lane >> 4) * 8 + j;
    float v;
    if (mode == 1) {
        int f = kk / Cp, c = kk % Cp;
        v = (c < C) ? W[(size_t)o * C * Fk + (size_t)c * Fk + f] : 0.f;
    } else if (mode == 2) {
        int f = kk >> 5, oo = kk & 31;
        v = W[(size_t)o * 480 + oo * 15 + f];
    } else {
        v = W[(size_t)o * C + kk];
    }
    P[e] = __float2bfloat16(v);
}

// copy 4 el rows (c-major (4,N)) into bf16 catT cols 0..3
__global__ void k_copy_el(const float* __restrict__ el, __hip_bfloat16* __restrict__ catT,
                          int N, int ld) {
    int n = blockIdx.x * 256 + threadIdx.x;
    if (n >= N) return;
#pragma unroll
    for (int j = 0; j < 4; ++j)
        catT[(size_t)n * ld + j] = __float2bfloat16(el[(size_t)j * N + n]);
}

// embed: X (32,N) c-major -> bf16 outT[n*ld + coff + o] = lrelu(W(O,32)@X + b)
__global__ __launch_bounds__(256) void k_embed(const float* __restrict__ X,
                                               const float* __restrict__ W,
                                               const float* __restrict__ b,
                                               __hip_bfloat16* __restrict__ outT,
                                               int N, int O, int ld, int coff) {
    __shared__ float Xs[32][65];
    int tid = threadIdx.x;
    int n0 = blockIdx.x * 64;
    for (int e = tid; e < 32 * 64; e += 256) {
        int nn = e & 63, c = e >> 6;
        Xs[c][nn] = X[(size_t)c * N + n0 + nn];
    }
    __syncthreads();
    int ol = tid & 63, nl = tid >> 6;
    for (int o0 = 0; o0 < O; o0 += 64) {
        int o = o0 + ol;
        float wv[32];
#pragma unroll
        for (int c = 0; c < 32; ++c) wv[c] = W[o * 32 + c];
        float bv = b[o];
        for (int nn = nl; nn < 64; nn += 4) {
            float acc = bv;
#pragma unroll
            for (int c = 0; c < 32; ++c) acc += wv[c] * Xs[c][nn];
            acc = acc >= 0.f ? acc : 0.1f * acc;
            outT[(size_t)(n0 + nn) * ld + coff + o] = __float2bfloat16(acc);
        }
    }
}

// ---------------------------------------------------------------------------
// MFMA GEMM with optional fused neighbor gather.
//   out[h][o] = act( sum_{f,c} Wb_packed * Ab[gather(f,h)][c] + bias[o] )
// Ab: bf16 [H][Cp] (Cp stride, zero-padded). Wb: packed by k_pack.
// Tile 64h x 64o, 4 waves (2x2), each wave 32x32 via 2x2 16x16x32 MFMA frags.
__global__ __launch_bounds__(256) void k_mfma_gemm(const __hip_bfloat16* __restrict__ Ab,
                                                   const int* __restrict__ nbrs,
                                                   const __hip_bfloat16* __restrict__ Wb,
                                                   const float* __restrict__ bias,
                                                   float* __restrict__ outF,
                                                   __hip_bfloat16* __restrict__ outB,
                                                   int Cp, int Fk, int O, int H, int act) {
    __shared__ short As[64 * 40];  // 64 rows x 32 bf16, padded to 40
    const unsigned short* A = (const unsigned short*)Ab;
    const unsigned short* Wp = (const unsigned short*)Wb;
    int tid = threadIdx.x;
    int lane = tid & 63, wid = tid >> 6;
    int wh = (wid >> 1) * 32;
    int wo = (wid & 1) * 32;
    int r = lane & 15, g = lane >> 4;
    int h0 = blockIdx.x * 64, o0 = blockIdx.y * 64;
    int srow = tid >> 2, sseg = tid & 3;
    int OT = O >> 4;
    int base_ot = (o0 + wo) >> 4;
    int CpT = Cp >> 5;

    f32x4 acc[2][2];
#pragma unroll
    for (int i = 0; i < 2; ++i)
#pragma unroll
        for (int j = 0; j < 2; ++j) acc[i][j] = (f32x4){0.f, 0.f, 0.f, 0.f};

    for (int f = 0; f < Fk; ++f) {
        int grow = nbrs ? nbrs[(size_t)f * H + h0 + srow] : (h0 + srow);
        const unsigned short* arow = A + (size_t)grow * Cp;
        for (int c0 = 0; c0 < Cp; c0 += 32) {
            bf16x8 v = *(const bf16x8*)(arow + c0 + sseg * 8);
            __syncthreads();
            *(bf16x8*)(&As[srow * 40 + sseg * 8]) = v;
            __syncthreads();
            int kt = f * CpT + (c0 >> 5);
            const unsigned short* wb = Wp + ((size_t)(kt * OT + base_ot) * 512 + lane * 8);
            bf16x8 b0 = *(const bf16x8*)(wb);
            bf16x8 b1 = *(const bf16x8*)(wb + 512);
            bf16x8 a0 = *(const bf16x8*)(&As[(wh + r) * 40 + g * 8]);
            bf16x8 a1 = *(const bf16x8*)(&As[(wh + 16 + r) * 40 + g * 8]);
            acc[0][0] = __builtin_amdgcn_mfma_f32_16x16x32_bf16(a0, b0, acc[0][0], 0, 0, 0);
            acc[0][1] = __builtin_amdgcn_mfma_f32_16x16x32_bf16(a0, b1, acc[0][1], 0, 0, 0);
            acc[1][0] = __builtin_amdgcn_mfma_f32_16x16x32_bf16(a1, b0, acc[1][0], 0, 0, 0);
            acc[1][1] = __builtin_amdgcn_mfma_f32_16x16x32_bf16(a1, b1, acc[1][1], 0, 0, 0);
        }
    }
#pragma unroll
    for (int mi = 0; mi < 2; ++mi)
#pragma unroll
        for (int ni = 0; ni < 2; ++ni) {
            int o = o0 + wo + ni * 16 + r;
            float bv = bias[o];
#pragma unroll
            for (int i = 0; i < 4; ++i) {
                int h = h0 + wh + mi * 16 + g * 4 + i;
                float v = acc[mi][ni][i] + bv;
                if (act) v = v >= 0.f ? v : 0.1f * v;
                if (outF) outF[(size_t)h * O + o] = v;
                if (outB) outB[(size_t)h * O + o] = __float2bfloat16(v);
            }
        }
}

// ---------------------------------------------------------------------------
// slice (fp32 out): outT[n*ld + coff + c] = sum_j latT[off[j][n]][c] * bary[j][n]
__global__ void k_slice(const float* __restrict__ latT, const float* __restrict__ bary,
                        const int* __restrict__ off, float* __restrict__ outT,
                        int N, int C, int ld, int coff) {
    int cl = threadIdx.x & 63, rr = threadIdx.x >> 6;
    int n = blockIdx.x * 4 + rr;
    int c = blockIdx.y * 64 + cl;
    float s = 0.f;
#pragma unroll
    for (int j = 0; j < 4; ++j) {
        int o = off[(size_t)j * N + n];
        float w = bary[(size_t)j * N + n];
        s += latT[(size_t)o * C + c] * w;
    }
    outT[(size_t)n * ld + coff + c] = s;
}

// slice (bf16 out)
__global__ void k_slice_b(const float* __restrict__ latT, const float* __restrict__ bary,
                          const int* __restrict__ off, __hip_bfloat16* __restrict__ outT,
                          int N, int C, int ld, int coff) {
    int cl = threadIdx.x & 63, rr = threadIdx.x >> 6;
    int n = blockIdx.x * 4 + rr;
    int c = blockIdx.y * 64 + cl;
    float s = 0.f;
#pragma unroll
    for (int j = 0; j < 4; ++j) {
        int o = off[(size_t)j * N + n];
        float w = bary[(size_t)j * N + n];
        s += latT[(size_t)o * C + c] * w;
    }
    outT[(size_t)n * ld + coff + c] = __float2bfloat16(s);
}

// splat: latT[off[j][n]][c] += featT[n][c] * bary[j][n]   (latT pre-zeroed)
__global__ void k_splat(const float* __restrict__ featT, const float* __restrict__ bary,
                        const int* __restrict__ off, float* __restrict__ latT,
                        int N, int C) {
    int cl = threadIdx.x & 63, rr = threadIdx.x >> 6;
    int n = blockIdx.x * 4 + rr;
    int c = blockIdx.y * 64 + cl;
    float v = featT[(size_t)n * C + c];
#pragma unroll
    for (int j = 0; j < 4; ++j) {
        int o = off[(size_t)j * N + n];
        float w = bary[(size_t)j * N + n];
        atomicAdd(&latT[(size_t)o * C + c], v * w);
    }
}

// ---------------------------------------------------------------------------
// fused correlation MLP (fp32 compute, bf16 out into h1T [h][f*32+o])
__global__ __launch_bounds__(256) void k_corr_mlp(const float* __restrict__ L1T,
                                                  const float* __restrict__ f2T,
                                                  const float* __restrict__ P1T,
                                                  const int* __restrict__ idx1,
                                                  const int* __restrict__ idx2,
                                                  const float* __restrict__ W0,
                                                  const float* __restrict__ b0,
                                                  const float* __restrict__ W1,
                                                  const float* __restrict__ b1,
                                                  __hip_bfloat16* __restrict__ h1T,
                                                  int H, int C1, int C2) {
    __shared__ float Ws[32][64];
    __shared__ float W1s[32][32];
    __shared__ float b0s[32], b1s[32];
    int tid = threadIdx.x;
    for (int e = tid; e < 1024; e += 256) W1s[e >> 5][e & 31] = W1[e];
    if (tid < 32) { b0s[tid] = b0[tid]; b1s[tid] = b1[tid]; }
    __syncthreads();
    int p = blockIdx.x * 256 + tid;
    int f = p >> 13;            // H == 8192
    int h = p & (HDIM - 1);
    int i1 = idx1[(size_t)f * H + h];
    int i2 = idx2[(size_t)f * H + h];
    float acc[32];
#pragma unroll
    for (int o = 0; o < 32; ++o) acc[o] = b0s[o];
    int K = C1 + C2;
    for (int c0 = 0; c0 < K; c0 += 64) {
        __syncthreads();
        for (int e = tid; e < 2048; e += 256) {
            int cc = e & 63, o = e >> 6;
            Ws[o][cc] = W0[(size_t)o * K + c0 + cc];
        }
        __syncthreads();
        if (c0 < C1) {
            const float4* a4 = (const float4*)(L1T + (size_t)i1 * C1 + c0);
            const float4* b4 = (const float4*)(f2T + (size_t)i2 * C1 + c0);
#pragma unroll 4
            for (int q = 0; q < 16; ++q) {
                float4 av = a4[q], bv = b4[q];
                float xs[4] = {av.x * bv.x, av.y * bv.y, av.z * bv.z, av.w * bv.w};
#pragma unroll
                for (int u = 0; u < 4; ++u) {
                    float xv = xs[u];
                    int cc = q * 4 + u;
#pragma unroll
                    for (int o = 0; o < 32; ++o) acc[o] = fmaf(Ws[o][cc], xv, acc[o]);
                }
            }
        } else {
            const float4* a4 = (const float4*)(P1T + (size_t)i1 * C2 + (c0 - C1));
#pragma unroll 4
            for (int q = 0; q < 16; ++q) {
                float4 av = a4[q];
                float xs[4] = {av.x, av.y, av.z, av.w};
#pragma unroll
                for (int u = 0; u < 4; ++u) {
                    float xv = xs[u];
                    int cc = q * 4 + u;
#pragma unroll
                    for (int o = 0; o < 32; ++o) acc[o] = fmaf(Ws[o][cc], xv, acc[o]);
                }
            }
        }
    }
    float a0[32];
#pragma unroll
    for (int o = 0; o < 32; ++o) {
        float x = acc[o];
        a0[o] = x >= 0.f ? x : 0.1f * x;
    }
    __hip_bfloat16* dst = h1T + (size_t)h * 480 + f * 32;
#pragma unroll
    for (int o = 0; o < 32; ++o) {
        float s = b1s[o];
#pragma unroll
        for (int i = 0; i < 32; ++i) s = fmaf(W1s[o][i], a0[i], s);
        s = s >= 0.f ? s : 0.1f * s;
        dst[o] = __float2bfloat16(s);
    }
}

// ---------------------------------------------------------------------------
// final 256 -> 3 head, writes (3, N) c-major
__global__ void k_final(const float* __restrict__ r2T, const float* __restrict__ W,
                        const float* __restrict__ b, float* __restrict__ out, int N) {
    int n = blockIdx.x * 256 + threadIdx.x;
    if (n >= N) return;
    float s0 = b[0], s1 = b[1], s2 = b[2];
    const float4* x4 = (const float4*)(r2T + (size_t)n * 256);
    for (int q = 0; q < 64; ++q) {
        float4 v = x4[q];
        float xs[4] = {v.x, v.y, v.z, v.w};
#pragma unroll
        for (int u = 0; u < 4; ++u) {
            int c = 4 * q + u;
            s0 = fmaf(W[c], xs[u], s0);
            s1 = fmaf(W[256 + c], xs[u], s1);
            s2 = fmaf(W[512 + c], xs[u], s2);
        }
    }
    out[n] = s0;
    out[(size_t)N + n] = s1;
    out[(size_t)2 * N + n] = s2;
}

// ---------------------------------------------------------------------------
extern "C" void kernel_launch(void* const* d_in, const int* in_sizes, int n_in,
                              void* d_out, int out_size, void* d_ws, size_t ws_size,
                              hipStream_t stream) {
    const int N = HDIM;
    auto F32 = [&](int i) { return (const float*)d_in[i]; };
    auto I32 = [&](int i) { return (const int*)d_in[i]; };

    char* base = (char*)d_ws;
    size_t off = 0;
    auto allocB = [&](size_t elems) -> __hip_bfloat16* {
        __hip_bfloat16* r = (__hip_bfloat16*)(base + off);
        off += ((elems * 2 + 255) / 256) * 256;
        return r;
    };
    auto allocF = [&](size_t elems) -> float* {
        float* r = (float*)(base + off);
        off += ((elems * 4 + 255) / 256) * 256;
        return r;
    };

    // packed bf16 weights
    __hip_bfloat16* pw_up2   = allocB((size_t)15 * 160 * 256);
    __hip_bfloat16* pw_up1   = allocB((size_t)15 * 544 * 512);
    __hip_bfloat16* pw_up2_1 = allocB((size_t)256 * 256);
    __hip_bfloat16* pw_up1_1 = allocB((size_t)512 * 512);
    __hip_bfloat16* pw_c2o   = allocB((size_t)480 * 256);
    __hip_bfloat16* pw_c2o1  = allocB((size_t)256 * 256);
    __hip_bfloat16* pw_c1o   = allocB((size_t)480 * 512);
    __hip_bfloat16* pw_c1o1  = allocB((size_t)512 * 512);
    __hip_bfloat16* pw_s4    = allocB((size_t)512 * 512);
    __hip_bfloat16* pw_s2    = allocB((size_t)512 * 256);
    // bf16 activations
    __hip_bfloat16* catb2  = allocB((size_t)N * 160);
    __hip_bfloat16* catb1a = allocB((size_t)N * 544);
    __hip_bfloat16* catb1b = allocB((size_t)N * 544);
    __hip_bfloat16* ab512  = allocB((size_t)N * 512);
    __hip_bfloat16* ab256  = allocB((size_t)N * 256);
    __hip_bfloat16* h1b    = allocB((size_t)N * 480);
    __hip_bfloat16* corr1b = allocB((size_t)N * 512);
    // fp32 buffers
    float* t512f  = allocF((size_t)N * 512);
    float* pcl512 = allocF((size_t)N * 512);   // pclA | pclB ; later SL512
    float* pcl01  = allocF((size_t)N * 512);
    float* pcl11  = allocF((size_t)N * 512);
    float* SL256  = allocF((size_t)N * 256);   // later SP256
    float* corr2T = allocF((size_t)N * 256);
    float* pclA = pcl512;
    float* pclB = pcl512 + (size_t)N * 256;
    float* SL512 = pcl512;
    float* SP256 = SL256;
    (void)ws_size; (void)in_sizes; (void)n_in; (void)out_size;

    // --- weight packing (bf16, MFMA fragment order) ---
    auto pack = [&](const float* W, __hip_bfloat16* P, int O, int C, int Cp, int Fk, int mode) {
        int total = Fk * Cp * O;
        k_pack<<<(total + 255) / 256, 256, 0, stream>>>(W, P, O, C, Cp, Fk, mode);
    };
    pack(F32(32), pw_up2,   256, 132, 160, 15, 1);
    pack(F32(36), pw_up1,   512, 516, 544, 15, 1);
    pack(F32(34), pw_up2_1, 256, 256, 256, 1, 0);
    pack(F32(38), pw_up1_1, 512, 512, 512, 1, 0);
    pack(F32(44), pw_c2o,   256, 480, 480, 1, 2);
    pack(F32(46), pw_c2o1,  256, 256, 256, 1, 0);
    pack(F32(52), pw_c1o,   512, 480, 480, 1, 2);
    pack(F32(54), pw_c1o1,  512, 512, 512, 1, 0);
    pack(F32(56), pw_s4,    512, 512, 512, 1, 0);
    pack(F32(58), pw_s2,    256, 512, 512, 1, 0);

    // --- zero-init (pads + splat accumulators) ---
    hipMemsetAsync(catb2,  0, (size_t)N * 160 * 2, stream);
    hipMemsetAsync(catb1a, 0, (size_t)N * 544 * 2, stream);
    hipMemsetAsync(catb1b, 0, (size_t)N * 544 * 2, stream);
    hipMemsetAsync(SL256,  0, (size_t)N * 256 * 4, stream);

    // --- Stage A: level-2 embed + blur + slices (per stream) ---
    auto stageA = [&](const float* el, const float* feat, const int* nbrs,
                      const float* baryA, const int* offA, float* pcl2,
                      const float* baryB, const int* offB, __hip_bfloat16* cat1dst) {
        k_copy_el<<<32, 256, 0, stream>>>(el, catb2, N, 160);
        k_embed<<<128, 256, 0, stream>>>(feat, F32(28), F32(29), catb2, N, 128, 160, 4);
        k_mfma_gemm<<<dim3(128, 4), 256, 0, stream>>>(catb2, nbrs, pw_up2, F32(33),
                                                      nullptr, ab256, 160, 15, 256, N, 1);
        k_mfma_gemm<<<dim3(128, 4), 256, 0, stream>>>(ab256, nullptr, pw_up2_1, F32(35),
                                                      t512f, nullptr, 256, 1, 256, N, 0);
        k_slice<<<dim3(2048, 4), 256, 0, stream>>>(t512f, baryA, offA, pcl2, N, 256, 256, 0);
        k_slice_b<<<dim3(2048, 4), 256, 0, stream>>>(t512f, baryB, offB, cat1dst, N, 256, 544, 4);
    };
    stageA(F32(6), F32(1), I32(20), F32(10), I32(15), pclA, F32(12), I32(17), catb1a);
    stageA(F32(7), F32(4), I32(21), F32(11), I32(16), pclB, F32(13), I32(18), catb1b);

    // --- Stage B: corr2 ---
    k_splat<<<dim3(2048, 4), 256, 0, stream>>>(pclA, F32(10), I32(15), SL256, N, 256);
    k_corr_mlp<<<FK * HDIM / 256, 256, 0, stream>>>(SL256, pclB, (const float*)nullptr,
                                                    I32(24), I32(25), F32(40), F32(41),
                                                    F32(42), F32(43), h1b, N, 256, 0);
    k_mfma_gemm<<<dim3(128, 4), 256, 0, stream>>>(h1b, nullptr, pw_c2o, F32(45),
                                                  nullptr, ab256, 480, 1, 256, N, 1);
    k_mfma_gemm<<<dim3(128, 4), 256, 0, stream>>>(ab256, nullptr, pw_c2o1, F32(47),
                                                  t512f, nullptr, 256, 1, 256, N, 0);
    k_slice<<<dim3(2048, 4), 256, 0, stream>>>(t512f, F32(12), I32(17), corr2T, N, 256, 256, 0);

    // --- Stage C: level-1 embed + blur + slices (per stream) ---
    auto stageC = [&](const float* el, const float* feat, const int* nbrs,
                      __hip_bfloat16* cat1, const float* baryO, const int* offO,
                      float* pclOut) {
        k_copy_el<<<32, 256, 0, stream>>>(el, cat1, N, 544);
        k_embed<<<128, 256, 0, stream>>>(feat, F32(30), F32(31), cat1, N, 256, 544, 260);
        k_mfma_gemm<<<dim3(128, 8), 256, 0, stream>>>(cat1, nbrs, pw_up1, F32(37),
                                                      nullptr, ab512, 544, 15, 512, N, 1);
        k_mfma_gemm<<<dim3(128, 8), 256, 0, stream>>>(ab512, nullptr, pw_up1_1, F32(39),
                                                      t512f, nullptr, 512, 1, 512, N, 0);
        k_slice<<<dim3(2048, 8), 256, 0, stream>>>(t512f, baryO, offO, pclOut, N, 512, 512, 0);
    };
    stageC(F32(8), F32(0), I32(22), catb1a, F32(12), I32(17), pcl01);
    stageC(F32(9), F32(3), I32(23), catb1b, F32(13), I32(18), pcl11);

    // --- Stage D: corr1 ---
    hipMemsetAsync(SL512, 0, (size_t)N * 512 * 4, stream);
    k_splat<<<dim3(2048, 8), 256, 0, stream>>>(pcl01, F32(12), I32(17), SL512, N, 512);
    hipMemsetAsync(SP256, 0, (size_t)N * 256 * 4, stream);
    k_splat<<<dim3(2048, 4), 256, 0, stream>>>(corr2T, F32(12), I32(17), SP256, N, 256);
    k_corr_mlp<<<FK * HDIM / 256, 256, 0, stream>>>(SL512, pcl11, SP256,
                                                    I32(26), I32(27), F32(48), F32(49),
                                                    F32(50), F32(51), h1b, N, 512, 256);
    k_mfma_gemm<<<dim3(128, 8), 256, 0, stream>>>(h1b, nullptr, pw_c1o, F32(53),
                                                  nullptr, ab512, 480, 1, 512, N, 1);
    k_mfma_gemm<<<dim3(128, 8), 256, 0, stream>>>(ab512, nullptr, pw_c1o1, F32(55),
                                                  t512f, nullptr, 512, 1, 512, N, 0);
    k_slice_b<<<dim3(2048, 8), 256, 0, stream>>>(t512f, F32(14), I32(19), corr1b, N, 512, 512, 0);

    // --- Stage E: head ---
    k_mfma_gemm<<<dim3(128, 8), 256, 0, stream>>>(corr1b, nullptr, pw_s4, F32(57),
                                                  nullptr, ab512, 512, 1, 512, N, 1);
    k_mfma_gemm<<<dim3(128, 4), 256, 0, stream>>>(ab512, nullptr, pw_s2, F32(59),
                                                  t512f, nullptr, 512, 1, 256, N, 1);
    k_final<<<32, 256, 0, stream>>>(t512f, F32(60), F32(61), (float*)d_out, N);
}

// Round 3
// 1063.238 us; speedup vs baseline: 4.9131x; 1.4246x over previous
//
#include <hip/hip_runtime.h>
#include <hip/hip_bf16.h>

#define HDIM 8192
#define FK 15

typedef __attribute__((ext_vector_type(8))) short bf16x8;
typedef __attribute__((ext_vector_type(4))) float f32x4;

// ---------------------------------------------------------------------------
// pack weights to bf16 in MFMA b-fragment order:
//   P[(kt*(O/16)+ot)*512 + lane*8 + j] = Wsrc[o = ot*16+(lane&15)][k' = kt*32+(lane>>4)*8+j]
// mode 0: dense  Wsrc[o][k'] = W[o*C + k']          (Cp == C)
// mode 1: blur   f=k'/Cp, c=k'%Cp; = c<C ? W[o*C*Fk + c*Fk + f] : 0
// mode 2: corr   f=k'/32, oo=k'%32; = W[o*480 + oo*15 + f]
__global__ void k_pack(const float* __restrict__ W, __hip_bfloat16* __restrict__ P,
                       int O, int C, int Cp, int Fk, int mode) {
    int e = blockIdx.x * 256 + threadIdx.x;
    int total = Fk * Cp * O;
    if (e >= total) return;
    int j = e & 7;
    int lane = (e >> 3) & 63;
    int tile = e >> 9;
    int OT = O >> 4;
    int ot = tile % OT, kt = tile / OT;
    int o = ot * 16 + (lane & 15);
    int kk = kt * 32 + (lane >> 4) * 8 + j;
    float v;
    if (mode == 1) {
        int f = kk / Cp, c = kk % Cp;
        v = (c < C) ? W[(size_t)o * C * Fk + (size_t)c * Fk + f] : 0.f;
    } else if (mode == 2) {
        int f = kk >> 5, oo = kk & 31;
        v = W[(size_t)o * 480 + oo * 15 + f];
    } else {
        v = W[(size_t)o * C + kk];
    }
    P[e] = __float2bfloat16(v);
}

// copy 4 el rows (c-major (4,N)) into bf16 catT cols 0..3
__global__ void k_copy_el(const float* __restrict__ el, __hip_bfloat16* __restrict__ catT,
                          int N, int ld) {
    int n = blockIdx.x * 256 + threadIdx.x;
    if (n >= N) return;
#pragma unroll
    for (int j = 0; j < 4; ++j)
        catT[(size_t)n * ld + j] = __float2bfloat16(el[(size_t)j * N + n]);
}

// embed: X (32,N) c-major -> bf16 outT[n*ld + coff + o] = lrelu(W(O,32)@X + b)
__global__ __launch_bounds__(256) void k_embed(const float* __restrict__ X,
                                               const float* __restrict__ W,
                                               const float* __restrict__ b,
                                               __hip_bfloat16* __restrict__ outT,
                                               int N, int O, int ld, int coff) {
    __shared__ float Xs[32][65];
    int tid = threadIdx.x;
    int n0 = blockIdx.x * 64;
    for (int e = tid; e < 32 * 64; e += 256) {
        int nn = e & 63, c = e >> 6;
        Xs[c][nn] = X[(size_t)c * N + n0 + nn];
    }
    __syncthreads();
    int ol = tid & 63, nl = tid >> 6;
    for (int o0 = 0; o0 < O; o0 += 64) {
        int o = o0 + ol;
        float wv[32];
#pragma unroll
        for (int c = 0; c < 32; ++c) wv[c] = W[o * 32 + c];
        float bv = b[o];
        for (int nn = nl; nn < 64; nn += 4) {
            float acc = bv;
#pragma unroll
            for (int c = 0; c < 32; ++c) acc += wv[c] * Xs[c][nn];
            acc = acc >= 0.f ? acc : 0.1f * acc;
            outT[(size_t)(n0 + nn) * ld + coff + o] = __float2bfloat16(acc);
        }
    }
}

// ---------------------------------------------------------------------------
// MFMA GEMM with optional fused neighbor gather.
__global__ __launch_bounds__(256) void k_mfma_gemm(const __hip_bfloat16* __restrict__ Ab,
                                                   const int* __restrict__ nbrs,
                                                   const __hip_bfloat16* __restrict__ Wb,
                                                   const float* __restrict__ bias,
                                                   float* __restrict__ outF,
                                                   __hip_bfloat16* __restrict__ outB,
                                                   int Cp, int Fk, int O, int H, int act) {
    __shared__ short As[64 * 40];
    const unsigned short* A = (const unsigned short*)Ab;
    const unsigned short* Wp = (const unsigned short*)Wb;
    int tid = threadIdx.x;
    int lane = tid & 63, wid = tid >> 6;
    int wh = (wid >> 1) * 32;
    int wo = (wid & 1) * 32;
    int r = lane & 15, g = lane >> 4;
    int h0 = blockIdx.x * 64, o0 = blockIdx.y * 64;
    int srow = tid >> 2, sseg = tid & 3;
    int OT = O >> 4;
    int base_ot = (o0 + wo) >> 4;
    int CpT = Cp >> 5;

    f32x4 acc[2][2];
#pragma unroll
    for (int i = 0; i < 2; ++i)
#pragma unroll
        for (int j = 0; j < 2; ++j) acc[i][j] = (f32x4){0.f, 0.f, 0.f, 0.f};

    for (int f = 0; f < Fk; ++f) {
        int grow = nbrs ? nbrs[(size_t)f * H + h0 + srow] : (h0 + srow);
        const unsigned short* arow = A + (size_t)grow * Cp;
        for (int c0 = 0; c0 < Cp; c0 += 32) {
            bf16x8 v = *(const bf16x8*)(arow + c0 + sseg * 8);
            __syncthreads();
            *(bf16x8*)(&As[srow * 40 + sseg * 8]) = v;
            __syncthreads();
            int kt = f * CpT + (c0 >> 5);
            const unsigned short* wb = Wp + ((size_t)(kt * OT + base_ot) * 512 + lane * 8);
            bf16x8 b0 = *(const bf16x8*)(wb);
            bf16x8 b1 = *(const bf16x8*)(wb + 512);
            bf16x8 a0 = *(const bf16x8*)(&As[(wh + r) * 40 + g * 8]);
            bf16x8 a1 = *(const bf16x8*)(&As[(wh + 16 + r) * 40 + g * 8]);
            acc[0][0] = __builtin_amdgcn_mfma_f32_16x16x32_bf16(a0, b0, acc[0][0], 0, 0, 0);
            acc[0][1] = __builtin_amdgcn_mfma_f32_16x16x32_bf16(a0, b1, acc[0][1], 0, 0, 0);
            acc[1][0] = __builtin_amdgcn_mfma_f32_16x16x32_bf16(a1, b0, acc[1][0], 0, 0, 0);
            acc[1][1] = __builtin_amdgcn_mfma_f32_16x16x32_bf16(a1, b1, acc[1][1], 0, 0, 0);
        }
    }
#pragma unroll
    for (int mi = 0; mi < 2; ++mi)
#pragma unroll
        for (int ni = 0; ni < 2; ++ni) {
            int o = o0 + wo + ni * 16 + r;
            float bv = bias[o];
#pragma unroll
            for (int i = 0; i < 4; ++i) {
                int h = h0 + wh + mi * 16 + g * 4 + i;
                float v = acc[mi][ni][i] + bv;
                if (act) v = v >= 0.f ? v : 0.1f * v;
                if (outF) outF[(size_t)h * O + o] = v;
                if (outB) outB[(size_t)h * O + o] = __float2bfloat16(v);
            }
        }
}

// ---------------------------------------------------------------------------
// slice (fp32 out)
__global__ void k_slice(const float* __restrict__ latT, const float* __restrict__ bary,
                        const int* __restrict__ off, float* __restrict__ outT,
                        int N, int C, int ld, int coff) {
    int cl = threadIdx.x & 63, rr = threadIdx.x >> 6;
    int n = blockIdx.x * 4 + rr;
    int c = blockIdx.y * 64 + cl;
    float s = 0.f;
#pragma unroll
    for (int j = 0; j < 4; ++j) {
        int o = off[(size_t)j * N + n];
        float w = bary[(size_t)j * N + n];
        s += latT[(size_t)o * C + c] * w;
    }
    outT[(size_t)n * ld + coff + c] = s;
}

// slice (bf16 out)
__global__ void k_slice_b(const float* __restrict__ latT, const float* __restrict__ bary,
                          const int* __restrict__ off, __hip_bfloat16* __restrict__ outT,
                          int N, int C, int ld, int coff) {
    int cl = threadIdx.x & 63, rr = threadIdx.x >> 6;
    int n = blockIdx.x * 4 + rr;
    int c = blockIdx.y * 64 + cl;
    float s = 0.f;
#pragma unroll
    for (int j = 0; j < 4; ++j) {
        int o = off[(size_t)j * N + n];
        float w = bary[(size_t)j * N + n];
        s += latT[(size_t)o * C + c] * w;
    }
    outT[(size_t)n * ld + coff + c] = __float2bfloat16(s);
}

// splat: latT[off[j][n]][c] += featT[n][c] * bary[j][n]   (latT pre-zeroed)
__global__ void k_splat(const float* __restrict__ featT, const float* __restrict__ bary,
                        const int* __restrict__ off, float* __restrict__ latT,
                        int N, int C) {
    int cl = threadIdx.x & 63, rr = threadIdx.x >> 6;
    int n = blockIdx.x * 4 + rr;
    int c = blockIdx.y * 64 + cl;
    float v = featT[(size_t)n * C + c];
#pragma unroll
    for (int j = 0; j < 4; ++j) {
        int o = off[(size_t)j * N + n];
        float w = bary[(size_t)j * N + n];
        atomicAdd(&latT[(size_t)o * C + c], v * w);
    }
}

// ---------------------------------------------------------------------------
// MFMA correlation MLP. Block = 64 positions (same f), 4 waves.
//   x[c] = L1T[i1][c] * f2T[i2][c] (c<C1), = P1T[i1][c-C1] (c>=C1), fp32 tables.
//   layer0: 32 outs over K=C1+C2 (MFMA, bf16 frags), lrelu
//   layer1: 32x32 (MFMA), lrelu -> h1T[h][f*32+o] bf16
__global__ __launch_bounds__(256) void k_corr_mfma(const float* __restrict__ L1T,
                                                   const float* __restrict__ f2T,
                                                   const float* __restrict__ P1T,
                                                   const int* __restrict__ idx1,
                                                   const int* __restrict__ idx2,
                                                   const __hip_bfloat16* __restrict__ W0p,
                                                   const float* __restrict__ b0,
                                                   const __hip_bfloat16* __restrict__ W1p,
                                                   const float* __restrict__ b1,
                                                   __hip_bfloat16* __restrict__ h1T,
                                                   int H, int C1, int C2) {
    __shared__ __hip_bfloat16 As[64 * 72];   // 64 pos x 64 ch, pad 72
    __shared__ __hip_bfloat16 A0s[64 * 40];  // 64 pos x 32 ch, pad 40
    __shared__ int i1s[64], i2s[64];
    int tid = threadIdx.x;
    int p0 = blockIdx.x * 64;
    int f = p0 >> 13;                 // H == 8192
    int h0 = p0 & (HDIM - 1);
    if (tid < 64) {
        i1s[tid] = idx1[(size_t)f * H + h0 + tid];
        i2s[tid] = idx2[(size_t)f * H + h0 + tid];
    }
    __syncthreads();
    int lane = tid & 63, wid = tid >> 6;
    int wh = wid * 16;
    int r16 = lane & 15, g = lane >> 4;
    int srow = tid >> 2, sseg = tid & 3;
    int K = C1 + C2;
    const unsigned short* W0u = (const unsigned short*)W0p;
    const unsigned short* W1u = (const unsigned short*)W1p;
    f32x4 acc[2];
    acc[0] = (f32x4){0.f, 0.f, 0.f, 0.f};
    acc[1] = (f32x4){0.f, 0.f, 0.f, 0.f};

    for (int c0 = 0; c0 < K; c0 += 64) {
        int cb = c0 + sseg * 16;
        float x[16];
        if (cb < C1) {
            const float4* a4 = (const float4*)(L1T + (size_t)i1s[srow] * C1 + cb);
            const float4* b4 = (const float4*)(f2T + (size_t)i2s[srow] * C1 + cb);
#pragma unroll
            for (int q = 0; q < 4; ++q) {
                float4 av = a4[q], bv = b4[q];
                x[q * 4 + 0] = av.x * bv.x; x[q * 4 + 1] = av.y * bv.y;
                x[q * 4 + 2] = av.z * bv.z; x[q * 4 + 3] = av.w * bv.w;
            }
        } else {
            const float4* a4 = (const float4*)(P1T + (size_t)i1s[srow] * C2 + (cb - C1));
#pragma unroll
            for (int q = 0; q < 4; ++q) {
                float4 av = a4[q];
                x[q * 4 + 0] = av.x; x[q * 4 + 1] = av.y;
                x[q * 4 + 2] = av.z; x[q * 4 + 3] = av.w;
            }
        }
        __syncthreads();  // previous chunk's MFMA reads of As complete
        __hip_bfloat16* dst = &As[srow * 72 + sseg * 16];
#pragma unroll
        for (int q = 0; q < 16; ++q) dst[q] = __float2bfloat16(x[q]);
        __syncthreads();
        int ktg = c0 >> 5;
#pragma unroll
        for (int kt = 0; kt < 2; ++kt) {
            bf16x8 a = *(const bf16x8*)(&As[(wh + r16) * 72 + kt * 32 + g * 8]);
            const unsigned short* wb = W0u + (size_t)((ktg + kt) * 2) * 512 + lane * 8;
            bf16x8 bf0 = *(const bf16x8*)(wb);
            bf16x8 bf1 = *(const bf16x8*)(wb + 512);
            acc[0] = __builtin_amdgcn_mfma_f32_16x16x32_bf16(a, bf0, acc[0], 0, 0, 0);
            acc[1] = __builtin_amdgcn_mfma_f32_16x16x32_bf16(a, bf1, acc[1], 0, 0, 0);
        }
    }
    // layer0 epilogue -> A0s (each wave touches only its own 16 rows)
    __syncthreads();
#pragma unroll
    for (int ot = 0; ot < 2; ++ot) {
        int o = ot * 16 + r16;
        float bv = b0[o];
#pragma unroll
        for (int i = 0; i < 4; ++i) {
            int pr = wh + g * 4 + i;
            float v = acc[ot][i] + bv;
            v = v >= 0.f ? v : 0.1f * v;
            A0s[pr * 40 + o] = __float2bfloat16(v);
        }
    }
    __syncthreads();
    // layer1: 32x32, K=32 (one k-tile)
    bf16x8 a1 = *(const bf16x8*)(&A0s[(wh + r16) * 40 + g * 8]);
    bf16x8 w1f0 = *(const bf16x8*)(W1u + lane * 8);
    bf16x8 w1f1 = *(const bf16x8*)(W1u + 512 + lane * 8);
    f32x4 acc1[2];
    acc1[0] = (f32x4){0.f, 0.f, 0.f, 0.f};
    acc1[1] = (f32x4){0.f, 0.f, 0.f, 0.f};
    acc1[0] = __builtin_amdgcn_mfma_f32_16x16x32_bf16(a1, w1f0, acc1[0], 0, 0, 0);
    acc1[1] = __builtin_amdgcn_mfma_f32_16x16x32_bf16(a1, w1f1, acc1[1], 0, 0, 0);
#pragma unroll
    for (int ot = 0; ot < 2; ++ot) {
        int o = ot * 16 + r16;
        float bv = b1[o];
#pragma unroll
        for (int i = 0; i < 4; ++i) {
            int h = h0 + wh + g * 4 + i;
            float v = acc1[ot][i] + bv;
            v = v >= 0.f ? v : 0.1f * v;
            h1T[(size_t)h * 480 + f * 32 + o] = __float2bfloat16(v);
        }
    }
}

// ---------------------------------------------------------------------------
// final 256 -> 3 head, writes (3, N) c-major
__global__ void k_final(const float* __restrict__ r2T, const float* __restrict__ W,
                        const float* __restrict__ b, float* __restrict__ out, int N) {
    int n = blockIdx.x * 256 + threadIdx.x;
    if (n >= N) return;
    float s0 = b[0], s1 = b[1], s2 = b[2];
    const float4* x4 = (const float4*)(r2T + (size_t)n * 256);
    for (int q = 0; q < 64; ++q) {
        float4 v = x4[q];
        float xs[4] = {v.x, v.y, v.z, v.w};
#pragma unroll
        for (int u = 0; u < 4; ++u) {
            int c = 4 * q + u;
            s0 = fmaf(W[c], xs[u], s0);
            s1 = fmaf(W[256 + c], xs[u], s1);
            s2 = fmaf(W[512 + c], xs[u], s2);
        }
    }
    out[n] = s0;
    out[(size_t)N + n] = s1;
    out[(size_t)2 * N + n] = s2;
}

// ---------------------------------------------------------------------------
extern "C" void kernel_launch(void* const* d_in, const int* in_sizes, int n_in,
                              void* d_out, int out_size, void* d_ws, size_t ws_size,
                              hipStream_t stream) {
    const int N = HDIM;
    auto F32 = [&](int i) { return (const float*)d_in[i]; };
    auto I32 = [&](int i) { return (const int*)d_in[i]; };

    char* base = (char*)d_ws;
    size_t off = 0;
    auto allocB = [&](size_t elems) -> __hip_bfloat16* {
        __hip_bfloat16* r = (__hip_bfloat16*)(base + off);
        off += ((elems * 2 + 255) / 256) * 256;
        return r;
    };
    auto allocF = [&](size_t elems) -> float* {
        float* r = (float*)(base + off);
        off += ((elems * 4 + 255) / 256) * 256;
        return r;
    };

    // packed bf16 weights
    __hip_bfloat16* pw_up2   = allocB((size_t)15 * 160 * 256);
    __hip_bfloat16* pw_up1   = allocB((size_t)15 * 544 * 512);
    __hip_bfloat16* pw_up2_1 = allocB((size_t)256 * 256);
    __hip_bfloat16* pw_up1_1 = allocB((size_t)512 * 512);
    __hip_bfloat16* pw_c2o   = allocB((size_t)480 * 256);
    __hip_bfloat16* pw_c2o1  = allocB((size_t)256 * 256);
    __hip_bfloat16* pw_c1o   = allocB((size_t)480 * 512);
    __hip_bfloat16* pw_c1o1  = allocB((size_t)512 * 512);
    __hip_bfloat16* pw_s4    = allocB((size_t)512 * 512);
    __hip_bfloat16* pw_s2    = allocB((size_t)512 * 256);
    __hip_bfloat16* pw_cc20  = allocB((size_t)256 * 32);
    __hip_bfloat16* pw_cc21  = allocB((size_t)32 * 32);
    __hip_bfloat16* pw_cc10  = allocB((size_t)768 * 32);
    __hip_bfloat16* pw_cc11  = allocB((size_t)32 * 32);
    // bf16 activations
    __hip_bfloat16* catb2  = allocB((size_t)N * 160);
    __hip_bfloat16* catb1a = allocB((size_t)N * 544);
    __hip_bfloat16* catb1b = allocB((size_t)N * 544);
    __hip_bfloat16* ab512  = allocB((size_t)N * 512);
    __hip_bfloat16* ab256  = allocB((size_t)N * 256);
    __hip_bfloat16* h1b    = allocB((size_t)N * 480);
    __hip_bfloat16* corr1b = allocB((size_t)N * 512);
    // fp32 buffers
    float* t512f  = allocF((size_t)N * 512);
    float* pcl512 = allocF((size_t)N * 512);   // pclA | pclB ; later SL512
    float* pcl01  = allocF((size_t)N * 512);
    float* pcl11  = allocF((size_t)N * 512);
    float* SL256  = allocF((size_t)N * 256);   // later SP256
    float* corr2T = allocF((size_t)N * 256);
    float* pclA = pcl512;
    float* pclB = pcl512 + (size_t)N * 256;
    float* SL512 = pcl512;
    float* SP256 = SL256;
    (void)ws_size; (void)in_sizes; (void)n_in; (void)out_size;

    // --- weight packing (bf16, MFMA fragment order) ---
    auto pack = [&](const float* W, __hip_bfloat16* P, int O, int C, int Cp, int Fk, int mode) {
        int total = Fk * Cp * O;
        k_pack<<<(total + 255) / 256, 256, 0, stream>>>(W, P, O, C, Cp, Fk, mode);
    };
    pack(F32(32), pw_up2,   256, 132, 160, 15, 1);
    pack(F32(36), pw_up1,   512, 516, 544, 15, 1);
    pack(F32(34), pw_up2_1, 256, 256, 256, 1, 0);
    pack(F32(38), pw_up1_1, 512, 512, 512, 1, 0);
    pack(F32(44), pw_c2o,   256, 480, 480, 1, 2);
    pack(F32(46), pw_c2o1,  256, 256, 256, 1, 0);
    pack(F32(52), pw_c1o,   512, 480, 480, 1, 2);
    pack(F32(54), pw_c1o1,  512, 512, 512, 1, 0);
    pack(F32(56), pw_s4,    512, 512, 512, 1, 0);
    pack(F32(58), pw_s2,    256, 512, 512, 1, 0);
    pack(F32(40), pw_cc20,  32, 256, 256, 1, 0);
    pack(F32(42), pw_cc21,  32, 32, 32, 1, 0);
    pack(F32(48), pw_cc10,  32, 768, 768, 1, 0);
    pack(F32(50), pw_cc11,  32, 32, 32, 1, 0);

    // --- zero-init (pads + splat accumulators) ---
    hipMemsetAsync(catb2,  0, (size_t)N * 160 * 2, stream);
    hipMemsetAsync(catb1a, 0, (size_t)N * 544 * 2, stream);
    hipMemsetAsync(catb1b, 0, (size_t)N * 544 * 2, stream);
    hipMemsetAsync(SL256,  0, (size_t)N * 256 * 4, stream);

    // --- Stage A: level-2 embed + blur + slices (per stream) ---
    auto stageA = [&](const float* el, const float* feat, const int* nbrs,
                      const float* baryA, const int* offA, float* pcl2,
                      const float* baryB, const int* offB, __hip_bfloat16* cat1dst) {
        k_copy_el<<<32, 256, 0, stream>>>(el, catb2, N, 160);
        k_embed<<<128, 256, 0, stream>>>(feat, F32(28), F32(29), catb2, N, 128, 160, 4);
        k_mfma_gemm<<<dim3(128, 4), 256, 0, stream>>>(catb2, nbrs, pw_up2, F32(33),
                                                      nullptr, ab256, 160, 15, 256, N, 1);
        k_mfma_gemm<<<dim3(128, 4), 256, 0, stream>>>(ab256, nullptr, pw_up2_1, F32(35),
                                                      t512f, nullptr, 256, 1, 256, N, 0);
        k_slice<<<dim3(2048, 4), 256, 0, stream>>>(t512f, baryA, offA, pcl2, N, 256, 256, 0);
        k_slice_b<<<dim3(2048, 4), 256, 0, stream>>>(t512f, baryB, offB, cat1dst, N, 256, 544, 4);
    };
    stageA(F32(6), F32(1), I32(20), F32(10), I32(15), pclA, F32(12), I32(17), catb1a);
    stageA(F32(7), F32(4), I32(21), F32(11), I32(16), pclB, F32(13), I32(18), catb1b);

    // --- Stage B: corr2 ---
    k_splat<<<dim3(2048, 4), 256, 0, stream>>>(pclA, F32(10), I32(15), SL256, N, 256);
    k_corr_mfma<<<FK * HDIM / 64, 256, 0, stream>>>(SL256, pclB, (const float*)nullptr,
                                                    I32(24), I32(25), pw_cc20, F32(41),
                                                    pw_cc21, F32(43), h1b, N, 256, 0);
    k_mfma_gemm<<<dim3(128, 4), 256, 0, stream>>>(h1b, nullptr, pw_c2o, F32(45),
                                                  nullptr, ab256, 480, 1, 256, N, 1);
    k_mfma_gemm<<<dim3(128, 4), 256, 0, stream>>>(ab256, nullptr, pw_c2o1, F32(47),
                                                  t512f, nullptr, 256, 1, 256, N, 0);
    k_slice<<<dim3(2048, 4), 256, 0, stream>>>(t512f, F32(12), I32(17), corr2T, N, 256, 256, 0);

    // --- Stage C: level-1 embed + blur + slices (per stream) ---
    auto stageC = [&](const float* el, const float* feat, const int* nbrs,
                      __hip_bfloat16* cat1, const float* baryO, const int* offO,
                      float* pclOut) {
        k_copy_el<<<32, 256, 0, stream>>>(el, cat1, N, 544);
        k_embed<<<128, 256, 0, stream>>>(feat, F32(30), F32(31), cat1, N, 256, 544, 260);
        k_mfma_gemm<<<dim3(128, 8), 256, 0, stream>>>(cat1, nbrs, pw_up1, F32(37),
                                                      nullptr, ab512, 544, 15, 512, N, 1);
        k_mfma_gemm<<<dim3(128, 8), 256, 0, stream>>>(ab512, nullptr, pw_up1_1, F32(39),
                                                      t512f, nullptr, 512, 1, 512, N, 0);
        k_slice<<<dim3(2048, 8), 256, 0, stream>>>(t512f, baryO, offO, pclOut, N, 512, 512, 0);
    };
    stageC(F32(8), F32(0), I32(22), catb1a, F32(12), I32(17), pcl01);
    stageC(F32(9), F32(3), I32(23), catb1b, F32(13), I32(18), pcl11);

    // --- Stage D: corr1 ---
    hipMemsetAsync(SL512, 0, (size_t)N * 512 * 4, stream);
    k_splat<<<dim3(2048, 8), 256, 0, stream>>>(pcl01, F32(12), I32(17), SL512, N, 512);
    hipMemsetAsync(SP256, 0, (size_t)N * 256 * 4, stream);
    k_splat<<<dim3(2048, 4), 256, 0, stream>>>(corr2T, F32(12), I32(17), SP256, N, 256);
    k_corr_mfma<<<FK * HDIM / 64, 256, 0, stream>>>(SL512, pcl11, SP256,
                                                    I32(26), I32(27), pw_cc10, F32(49),
                                                    pw_cc11, F32(51), h1b, N, 512, 256);
    k_mfma_gemm<<<dim3(128, 8), 256, 0, stream>>>(h1b, nullptr, pw_c1o, F32(53),
                                                  nullptr, ab512, 480, 1, 512, N, 1);
    k_mfma_gemm<<<dim3(128, 8), 256, 0, stream>>>(ab512, nullptr, pw_c1o1, F32(55),
                                                  t512f, nullptr, 512, 1, 512, N, 0);
    k_slice_b<<<dim3(2048, 8), 256, 0, stream>>>(t512f, F32(14), I32(19), corr1b, N, 512, 512, 0);

    // --- Stage E: head ---
    k_mfma_gemm<<<dim3(128, 8), 256, 0, stream>>>(corr1b, nullptr, pw_s4, F32(57),
                                                  nullptr, ab512, 512, 1, 512, N, 1);
    k_mfma_gemm<<<dim3(128, 4), 256, 0, stream>>>(ab512, nullptr, pw_s2, F32(59),
                                                  t512f, nullptr, 512, 1, 256, N, 1);
    k_final<<<32, 256, 0, stream>>>(t512f, F32(60), F32(61), (float*)d_out, N);
}

// Round 4
// 977.602 us; speedup vs baseline: 5.3434x; 1.0876x over previous
//
#include <hip/hip_runtime.h>
#include <hip/hip_bf16.h>

#define HDIM 8192
#define FK 15

typedef __attribute__((ext_vector_type(8))) short bf16x8;
typedef __attribute__((ext_vector_type(4))) float f32x4;

// ---------------------------------------------------------------------------
// pack weights to bf16 in MFMA b-fragment order:
//   P[(kt*(O/16)+ot)*512 + lane*8 + j] = Wsrc[o = ot*16+(lane&15)][k' = kt*32+(lane>>4)*8+j]
// mode 0: dense  Wsrc[o][k'] = W[o*C + k']          (Cp == C)
// mode 1: blur   f=k'/Cp, c=k'%Cp; = c<C ? W[o*C*Fk + c*Fk + f] : 0
// mode 2: corr   f=k'/32, oo=k'%32; = W[o*480 + oo*15 + f]
__global__ void k_pack(const float* __restrict__ W, __hip_bfloat16* __restrict__ P,
                       int O, int C, int Cp, int Fk, int mode) {
    int e = blockIdx.x * 256 + threadIdx.x;
    int total = Fk * Cp * O;
    if (e >= total) return;
    int j = e & 7;
    int lane = (e >> 3) & 63;
    int tile = e >> 9;
    int OT = O >> 4;
    int ot = tile % OT, kt = tile / OT;
    int o = ot * 16 + (lane & 15);
    int kk = kt * 32 + (lane >> 4) * 8 + j;
    float v;
    if (mode == 1) {
        int f = kk / Cp, c = kk % Cp;
        v = (c < C) ? W[(size_t)o * C * Fk + (size_t)c * Fk + f] : 0.f;
    } else if (mode == 2) {
        int f = kk >> 5, oo = kk & 31;
        v = W[(size_t)o * 480 + oo * 15 + f];
    } else {
        v = W[(size_t)o * C + kk];
    }
    P[e] = __float2bfloat16(v);
}

// copy 4 el rows (c-major (4,N)) into bf16 catT cols 0..3
__global__ void k_copy_el(const float* __restrict__ el, __hip_bfloat16* __restrict__ catT,
                          int N, int ld) {
    int n = blockIdx.x * 256 + threadIdx.x;
    if (n >= N) return;
#pragma unroll
    for (int j = 0; j < 4; ++j)
        catT[(size_t)n * ld + j] = __float2bfloat16(el[(size_t)j * N + n]);
}

// embed: X (32,N) c-major -> bf16 outT[n*ld + coff + o] = lrelu(W(O,32)@X + b)
__global__ __launch_bounds__(256) void k_embed(const float* __restrict__ X,
                                               const float* __restrict__ W,
                                               const float* __restrict__ b,
                                               __hip_bfloat16* __restrict__ outT,
                                               int N, int O, int ld, int coff) {
    __shared__ float Xs[32][65];
    int tid = threadIdx.x;
    int n0 = blockIdx.x * 64;
    for (int e = tid; e < 32 * 64; e += 256) {
        int nn = e & 63, c = e >> 6;
        Xs[c][nn] = X[(size_t)c * N + n0 + nn];
    }
    __syncthreads();
    int ol = tid & 63, nl = tid >> 6;
    for (int o0 = 0; o0 < O; o0 += 64) {
        int o = o0 + ol;
        float wv[32];
#pragma unroll
        for (int c = 0; c < 32; ++c) wv[c] = W[o * 32 + c];
        float bv = b[o];
        for (int nn = nl; nn < 64; nn += 4) {
            float acc = bv;
#pragma unroll
            for (int c = 0; c < 32; ++c) acc += wv[c] * Xs[c][nn];
            acc = acc >= 0.f ? acc : 0.1f * acc;
            outT[(size_t)(n0 + nn) * ld + coff + o] = __float2bfloat16(acc);
        }
    }
}

// ---------------------------------------------------------------------------
// MFMA GEMM, 128h x 64o tile, 4 waves (each 64h x 32o = 4x2 frags, 8 MFMA/step),
// double-buffered LDS A with ONE barrier per K=32 step; gathered A rows; packed
// bf16 weights loaded straight to registers (coalesced, L2-resident); neighbor
// indices staged in LDS once.
__global__ __launch_bounds__(256) void k_mfma_gemm(const __hip_bfloat16* __restrict__ Ab,
                                                   const int* __restrict__ nbrs,
                                                   const __hip_bfloat16* __restrict__ Wb,
                                                   const float* __restrict__ bias,
                                                   float* __restrict__ outF,
                                                   __hip_bfloat16* __restrict__ outB,
                                                   int Cp, int Fk, int O, int H, int act) {
    __shared__ short As[2][128 * 40];   // 128 rows x 32 bf16, pad 40 (conflict-free)
    __shared__ int idx_s[FK * 128];
    const unsigned short* A = (const unsigned short*)Ab;
    const unsigned short* Wp = (const unsigned short*)Wb;
    int tid = threadIdx.x;
    int lane = tid & 63, wid = tid >> 6;
    int wh = (wid >> 1) * 64;          // wave row base (0 / 64)
    int wo = (wid & 1) * 32;           // wave col base (0 / 32)
    int r16 = lane & 15, g = lane >> 4;
    int h0 = blockIdx.x * 128, o0 = blockIdx.y * 64;
    int row0 = tid >> 2, seg = tid & 3;  // staging: rows row0 and row0+64, 16B seg
    int OT = O >> 4;
    int CpT = Cp >> 5;
    int S = Fk * CpT;
    int base_ot = (o0 + wo) >> 4;

    for (int e = tid; e < Fk * 128; e += 256)
        idx_s[e] = nbrs ? nbrs[(size_t)(e >> 7) * H + h0 + (e & 127)] : (h0 + (e & 127));
    __syncthreads();

    f32x4 acc[4][2];
#pragma unroll
    for (int mi = 0; mi < 4; ++mi)
#pragma unroll
        for (int ni = 0; ni < 2; ++ni) acc[mi][ni] = (f32x4){0.f, 0.f, 0.f, 0.f};

    // prologue: stage step 0 into buf0, preload step-0 b-frags
    {
        int gi0 = idx_s[row0];
        int gi1 = idx_s[64 + row0];
        bf16x8 v0 = *(const bf16x8*)(A + (size_t)gi0 * Cp + seg * 8);
        bf16x8 v1 = *(const bf16x8*)(A + (size_t)gi1 * Cp + seg * 8);
        *(bf16x8*)(&As[0][row0 * 40 + seg * 8]) = v0;
        *(bf16x8*)(&As[0][(64 + row0) * 40 + seg * 8]) = v1;
    }
    bf16x8 bc0 = *(const bf16x8*)(Wp + ((size_t)base_ot) * 512 + lane * 8);
    bf16x8 bc1 = *(const bf16x8*)(Wp + ((size_t)(base_ot + 1)) * 512 + lane * 8);

    int f_idx = 0, c_idx = 0;
    for (int s = 0; s < S; ++s) {
        int cur = s & 1;
        bool hn = (s + 1 < S);
        int cn = c_idx + 1, fn = f_idx;
        if (cn == CpT) { cn = 0; ++fn; }
        bf16x8 vn0, vn1, bn0, bn1;
        if (hn) {
            int gj0 = idx_s[fn * 128 + row0];
            int gj1 = idx_s[fn * 128 + 64 + row0];
            vn0 = *(const bf16x8*)(A + (size_t)gj0 * Cp + cn * 32 + seg * 8);
            vn1 = *(const bf16x8*)(A + (size_t)gj1 * Cp + cn * 32 + seg * 8);
            int ktn = fn * CpT + cn;
            bn0 = *(const bf16x8*)(Wp + ((size_t)(ktn * OT + base_ot)) * 512 + lane * 8);
            bn1 = *(const bf16x8*)(Wp + ((size_t)(ktn * OT + base_ot + 1)) * 512 + lane * 8);
        }
        __syncthreads();   // buf[cur] writes visible; prior reads of buf[cur^1] done
        bf16x8 a0 = *(const bf16x8*)(&As[cur][(wh + r16) * 40 + g * 8]);
        bf16x8 a1 = *(const bf16x8*)(&As[cur][(wh + 16 + r16) * 40 + g * 8]);
        bf16x8 a2 = *(const bf16x8*)(&As[cur][(wh + 32 + r16) * 40 + g * 8]);
        bf16x8 a3 = *(const bf16x8*)(&As[cur][(wh + 48 + r16) * 40 + g * 8]);
        acc[0][0] = __builtin_amdgcn_mfma_f32_16x16x32_bf16(a0, bc0, acc[0][0], 0, 0, 0);
        acc[0][1] = __builtin_amdgcn_mfma_f32_16x16x32_bf16(a0, bc1, acc[0][1], 0, 0, 0);
        acc[1][0] = __builtin_amdgcn_mfma_f32_16x16x32_bf16(a1, bc0, acc[1][0], 0, 0, 0);
        acc[1][1] = __builtin_amdgcn_mfma_f32_16x16x32_bf16(a1, bc1, acc[1][1], 0, 0, 0);
        acc[2][0] = __builtin_amdgcn_mfma_f32_16x16x32_bf16(a2, bc0, acc[2][0], 0, 0, 0);
        acc[2][1] = __builtin_amdgcn_mfma_f32_16x16x32_bf16(a2, bc1, acc[2][1], 0, 0, 0);
        acc[3][0] = __builtin_amdgcn_mfma_f32_16x16x32_bf16(a3, bc0, acc[3][0], 0, 0, 0);
        acc[3][1] = __builtin_amdgcn_mfma_f32_16x16x32_bf16(a3, bc1, acc[3][1], 0, 0, 0);
        if (hn) {
            *(bf16x8*)(&As[cur ^ 1][row0 * 40 + seg * 8]) = vn0;
            *(bf16x8*)(&As[cur ^ 1][(64 + row0) * 40 + seg * 8]) = vn1;
            bc0 = bn0; bc1 = bn1;
        }
        c_idx = cn; f_idx = fn;
    }

#pragma unroll
    for (int ni = 0; ni < 2; ++ni) {
        int o = o0 + wo + ni * 16 + r16;
        float bv = bias[o];
#pragma unroll
        for (int mi = 0; mi < 4; ++mi) {
#pragma unroll
            for (int i = 0; i < 4; ++i) {
                int h = h0 + wh + mi * 16 + g * 4 + i;
                float v = acc[mi][ni][i] + bv;
                if (act) v = v >= 0.f ? v : 0.1f * v;
                if (outF) outF[(size_t)h * O + o] = v;
                if (outB) outB[(size_t)h * O + o] = __float2bfloat16(v);
            }
        }
    }
}

// ---------------------------------------------------------------------------
// slice (fp32 out)
__global__ void k_slice(const float* __restrict__ latT, const float* __restrict__ bary,
                        const int* __restrict__ off, float* __restrict__ outT,
                        int N, int C, int ld, int coff) {
    int cl = threadIdx.x & 63, rr = threadIdx.x >> 6;
    int n = blockIdx.x * 4 + rr;
    int c = blockIdx.y * 64 + cl;
    float s = 0.f;
#pragma unroll
    for (int j = 0; j < 4; ++j) {
        int o = off[(size_t)j * N + n];
        float w = bary[(size_t)j * N + n];
        s += latT[(size_t)o * C + c] * w;
    }
    outT[(size_t)n * ld + coff + c] = s;
}

// slice (bf16 out)
__global__ void k_slice_b(const float* __restrict__ latT, const float* __restrict__ bary,
                          const int* __restrict__ off, __hip_bfloat16* __restrict__ outT,
                          int N, int C, int ld, int coff) {
    int cl = threadIdx.x & 63, rr = threadIdx.x >> 6;
    int n = blockIdx.x * 4 + rr;
    int c = blockIdx.y * 64 + cl;
    float s = 0.f;
#pragma unroll
    for (int j = 0; j < 4; ++j) {
        int o = off[(size_t)j * N + n];
        float w = bary[(size_t)j * N + n];
        s += latT[(size_t)o * C + c] * w;
    }
    outT[(size_t)n * ld + coff + c] = __float2bfloat16(s);
}

// splat: latT[off[j][n]][c] += featT[n][c] * bary[j][n]   (latT pre-zeroed)
__global__ void k_splat(const float* __restrict__ featT, const float* __restrict__ bary,
                        const int* __restrict__ off, float* __restrict__ latT,
                        int N, int C) {
    int cl = threadIdx.x & 63, rr = threadIdx.x >> 6;
    int n = blockIdx.x * 4 + rr;
    int c = blockIdx.y * 64 + cl;
    float v = featT[(size_t)n * C + c];
#pragma unroll
    for (int j = 0; j < 4; ++j) {
        int o = off[(size_t)j * N + n];
        float w = bary[(size_t)j * N + n];
        atomicAdd(&latT[(size_t)o * C + c], v * w);
    }
}

// ---------------------------------------------------------------------------
// MFMA correlation MLP. Block = 64 positions (same f), 4 waves.
__global__ __launch_bounds__(256) void k_corr_mfma(const float* __restrict__ L1T,
                                                   const float* __restrict__ f2T,
                                                   const float* __restrict__ P1T,
                                                   const int* __restrict__ idx1,
                                                   const int* __restrict__ idx2,
                                                   const __hip_bfloat16* __restrict__ W0p,
                                                   const float* __restrict__ b0,
                                                   const __hip_bfloat16* __restrict__ W1p,
                                                   const float* __restrict__ b1,
                                                   __hip_bfloat16* __restrict__ h1T,
                                                   int H, int C1, int C2) {
    __shared__ __hip_bfloat16 As[64 * 72];   // 64 pos x 64 ch, pad 72
    __shared__ __hip_bfloat16 A0s[64 * 40];  // 64 pos x 32 ch, pad 40
    __shared__ int i1s[64], i2s[64];
    int tid = threadIdx.x;
    int p0 = blockIdx.x * 64;
    int f = p0 >> 13;                 // H == 8192
    int h0 = p0 & (HDIM - 1);
    if (tid < 64) {
        i1s[tid] = idx1[(size_t)f * H + h0 + tid];
        i2s[tid] = idx2[(size_t)f * H + h0 + tid];
    }
    __syncthreads();
    int lane = tid & 63, wid = tid >> 6;
    int wh = wid * 16;
    int r16 = lane & 15, g = lane >> 4;
    int srow = tid >> 2, sseg = tid & 3;
    int K = C1 + C2;
    const unsigned short* W0u = (const unsigned short*)W0p;
    const unsigned short* W1u = (const unsigned short*)W1p;
    f32x4 acc[2];
    acc[0] = (f32x4){0.f, 0.f, 0.f, 0.f};
    acc[1] = (f32x4){0.f, 0.f, 0.f, 0.f};

    for (int c0 = 0; c0 < K; c0 += 64) {
        int cb = c0 + sseg * 16;
        float x[16];
        if (cb < C1) {
            const float4* a4 = (const float4*)(L1T + (size_t)i1s[srow] * C1 + cb);
            const float4* b4 = (const float4*)(f2T + (size_t)i2s[srow] * C1 + cb);
#pragma unroll
            for (int q = 0; q < 4; ++q) {
                float4 av = a4[q], bv = b4[q];
                x[q * 4 + 0] = av.x * bv.x; x[q * 4 + 1] = av.y * bv.y;
                x[q * 4 + 2] = av.z * bv.z; x[q * 4 + 3] = av.w * bv.w;
            }
        } else {
            const float4* a4 = (const float4*)(P1T + (size_t)i1s[srow] * C2 + (cb - C1));
#pragma unroll
            for (int q = 0; q < 4; ++q) {
                float4 av = a4[q];
                x[q * 4 + 0] = av.x; x[q * 4 + 1] = av.y;
                x[q * 4 + 2] = av.z; x[q * 4 + 3] = av.w;
            }
        }
        __syncthreads();  // previous chunk's MFMA reads of As complete
        __hip_bfloat16* dst = &As[srow * 72 + sseg * 16];
#pragma unroll
        for (int q = 0; q < 16; ++q) dst[q] = __float2bfloat16(x[q]);
        __syncthreads();
        int ktg = c0 >> 5;
#pragma unroll
        for (int kt = 0; kt < 2; ++kt) {
            bf16x8 a = *(const bf16x8*)(&As[(wh + r16) * 72 + kt * 32 + g * 8]);
            const unsigned short* wb = W0u + (size_t)((ktg + kt) * 2) * 512 + lane * 8;
            bf16x8 bf0 = *(const bf16x8*)(wb);
            bf16x8 bf1 = *(const bf16x8*)(wb + 512);
            acc[0] = __builtin_amdgcn_mfma_f32_16x16x32_bf16(a, bf0, acc[0], 0, 0, 0);
            acc[1] = __builtin_amdgcn_mfma_f32_16x16x32_bf16(a, bf1, acc[1], 0, 0, 0);
        }
    }
    // layer0 epilogue -> A0s (each wave touches only its own 16 rows)
    __syncthreads();
#pragma unroll
    for (int ot = 0; ot < 2; ++ot) {
        int o = ot * 16 + r16;
        float bv = b0[o];
#pragma unroll
        for (int i = 0; i < 4; ++i) {
            int pr = wh + g * 4 + i;
            float v = acc[ot][i] + bv;
            v = v >= 0.f ? v : 0.1f * v;
            A0s[pr * 40 + o] = __float2bfloat16(v);
        }
    }
    __syncthreads();
    // layer1: 32x32, K=32 (one k-tile)
    bf16x8 a1 = *(const bf16x8*)(&A0s[(wh + r16) * 40 + g * 8]);
    bf16x8 w1f0 = *(const bf16x8*)(W1u + lane * 8);
    bf16x8 w1f1 = *(const bf16x8*)(W1u + 512 + lane * 8);
    f32x4 acc1[2];
    acc1[0] = (f32x4){0.f, 0.f, 0.f, 0.f};
    acc1[1] = (f32x4){0.f, 0.f, 0.f, 0.f};
    acc1[0] = __builtin_amdgcn_mfma_f32_16x16x32_bf16(a1, w1f0, acc1[0], 0, 0, 0);
    acc1[1] = __builtin_amdgcn_mfma_f32_16x16x32_bf16(a1, w1f1, acc1[1], 0, 0, 0);
#pragma unroll
    for (int ot = 0; ot < 2; ++ot) {
        int o = ot * 16 + r16;
        float bv = b1[o];
#pragma unroll
        for (int i = 0; i < 4; ++i) {
            int h = h0 + wh + g * 4 + i;
            float v = acc1[ot][i] + bv;
            v = v >= 0.f ? v : 0.1f * v;
            h1T[(size_t)h * 480 + f * 32 + o] = __float2bfloat16(v);
        }
    }
}

// ---------------------------------------------------------------------------
// final 256 -> 3 head, writes (3, N) c-major
__global__ void k_final(const float* __restrict__ r2T, const float* __restrict__ W,
                        const float* __restrict__ b, float* __restrict__ out, int N) {
    int n = blockIdx.x * 256 + threadIdx.x;
    if (n >= N) return;
    float s0 = b[0], s1 = b[1], s2 = b[2];
    const float4* x4 = (const float4*)(r2T + (size_t)n * 256);
    for (int q = 0; q < 64; ++q) {
        float4 v = x4[q];
        float xs[4] = {v.x, v.y, v.z, v.w};
#pragma unroll
        for (int u = 0; u < 4; ++u) {
            int c = 4 * q + u;
            s0 = fmaf(W[c], xs[u], s0);
            s1 = fmaf(W[256 + c], xs[u], s1);
            s2 = fmaf(W[512 + c], xs[u], s2);
        }
    }
    out[n] = s0;
    out[(size_t)N + n] = s1;
    out[(size_t)2 * N + n] = s2;
}

// ---------------------------------------------------------------------------
extern "C" void kernel_launch(void* const* d_in, const int* in_sizes, int n_in,
                              void* d_out, int out_size, void* d_ws, size_t ws_size,
                              hipStream_t stream) {
    const int N = HDIM;
    auto F32 = [&](int i) { return (const float*)d_in[i]; };
    auto I32 = [&](int i) { return (const int*)d_in[i]; };

    char* base = (char*)d_ws;
    size_t off = 0;
    auto allocB = [&](size_t elems) -> __hip_bfloat16* {
        __hip_bfloat16* r = (__hip_bfloat16*)(base + off);
        off += ((elems * 2 + 255) / 256) * 256;
        return r;
    };
    auto allocF = [&](size_t elems) -> float* {
        float* r = (float*)(base + off);
        off += ((elems * 4 + 255) / 256) * 256;
        return r;
    };

    // packed bf16 weights
    __hip_bfloat16* pw_up2   = allocB((size_t)15 * 160 * 256);
    __hip_bfloat16* pw_up1   = allocB((size_t)15 * 544 * 512);
    __hip_bfloat16* pw_up2_1 = allocB((size_t)256 * 256);
    __hip_bfloat16* pw_up1_1 = allocB((size_t)512 * 512);
    __hip_bfloat16* pw_c2o   = allocB((size_t)480 * 256);
    __hip_bfloat16* pw_c2o1  = allocB((size_t)256 * 256);
    __hip_bfloat16* pw_c1o   = allocB((size_t)480 * 512);
    __hip_bfloat16* pw_c1o1  = allocB((size_t)512 * 512);
    __hip_bfloat16* pw_s4    = allocB((size_t)512 * 512);
    __hip_bfloat16* pw_s2    = allocB((size_t)512 * 256);
    __hip_bfloat16* pw_cc20  = allocB((size_t)256 * 32);
    __hip_bfloat16* pw_cc21  = allocB((size_t)32 * 32);
    __hip_bfloat16* pw_cc10  = allocB((size_t)768 * 32);
    __hip_bfloat16* pw_cc11  = allocB((size_t)32 * 32);
    // bf16 activations
    __hip_bfloat16* catb2  = allocB((size_t)N * 160);
    __hip_bfloat16* catb1a = allocB((size_t)N * 544);
    __hip_bfloat16* catb1b = allocB((size_t)N * 544);
    __hip_bfloat16* ab512  = allocB((size_t)N * 512);
    __hip_bfloat16* ab256  = allocB((size_t)N * 256);
    __hip_bfloat16* h1b    = allocB((size_t)N * 480);
    __hip_bfloat16* corr1b = allocB((size_t)N * 512);
    // fp32 buffers
    float* t512f  = allocF((size_t)N * 512);
    float* pcl512 = allocF((size_t)N * 512);   // pclA | pclB ; later SL512
    float* pcl01  = allocF((size_t)N * 512);
    float* pcl11  = allocF((size_t)N * 512);
    float* SL256  = allocF((size_t)N * 256);   // later SP256
    float* corr2T = allocF((size_t)N * 256);
    float* pclA = pcl512;
    float* pclB = pcl512 + (size_t)N * 256;
    float* SL512 = pcl512;
    float* SP256 = SL256;
    (void)ws_size; (void)in_sizes; (void)n_in; (void)out_size;

    // --- weight packing (bf16, MFMA fragment order) ---
    auto pack = [&](const float* W, __hip_bfloat16* P, int O, int C, int Cp, int Fk, int mode) {
        int total = Fk * Cp * O;
        k_pack<<<(total + 255) / 256, 256, 0, stream>>>(W, P, O, C, Cp, Fk, mode);
    };
    pack(F32(32), pw_up2,   256, 132, 160, 15, 1);
    pack(F32(36), pw_up1,   512, 516, 544, 15, 1);
    pack(F32(34), pw_up2_1, 256, 256, 256, 1, 0);
    pack(F32(38), pw_up1_1, 512, 512, 512, 1, 0);
    pack(F32(44), pw_c2o,   256, 480, 480, 1, 2);
    pack(F32(46), pw_c2o1,  256, 256, 256, 1, 0);
    pack(F32(52), pw_c1o,   512, 480, 480, 1, 2);
    pack(F32(54), pw_c1o1,  512, 512, 512, 1, 0);
    pack(F32(56), pw_s4,    512, 512, 512, 1, 0);
    pack(F32(58), pw_s2,    256, 512, 512, 1, 0);
    pack(F32(40), pw_cc20,  32, 256, 256, 1, 0);
    pack(F32(42), pw_cc21,  32, 32, 32, 1, 0);
    pack(F32(48), pw_cc10,  32, 768, 768, 1, 0);
    pack(F32(50), pw_cc11,  32, 32, 32, 1, 0);

    // --- zero-init (pads + splat accumulators) ---
    hipMemsetAsync(catb2,  0, (size_t)N * 160 * 2, stream);
    hipMemsetAsync(catb1a, 0, (size_t)N * 544 * 2, stream);
    hipMemsetAsync(catb1b, 0, (size_t)N * 544 * 2, stream);
    hipMemsetAsync(SL256,  0, (size_t)N * 256 * 4, stream);

    // --- Stage A: level-2 embed + blur + slices (per stream) ---
    auto stageA = [&](const float* el, const float* feat, const int* nbrs,
                      const float* baryA, const int* offA, float* pcl2,
                      const float* baryB, const int* offB, __hip_bfloat16* cat1dst) {
        k_copy_el<<<32, 256, 0, stream>>>(el, catb2, N, 160);
        k_embed<<<128, 256, 0, stream>>>(feat, F32(28), F32(29), catb2, N, 128, 160, 4);
        k_mfma_gemm<<<dim3(64, 4), 256, 0, stream>>>(catb2, nbrs, pw_up2, F32(33),
                                                     nullptr, ab256, 160, 15, 256, N, 1);
        k_mfma_gemm<<<dim3(64, 4), 256, 0, stream>>>(ab256, nullptr, pw_up2_1, F32(35),
                                                     t512f, nullptr, 256, 1, 256, N, 0);
        k_slice<<<dim3(2048, 4), 256, 0, stream>>>(t512f, baryA, offA, pcl2, N, 256, 256, 0);
        k_slice_b<<<dim3(2048, 4), 256, 0, stream>>>(t512f, baryB, offB, cat1dst, N, 256, 544, 4);
    };
    stageA(F32(6), F32(1), I32(20), F32(10), I32(15), pclA, F32(12), I32(17), catb1a);
    stageA(F32(7), F32(4), I32(21), F32(11), I32(16), pclB, F32(13), I32(18), catb1b);

    // --- Stage B: corr2 ---
    k_splat<<<dim3(2048, 4), 256, 0, stream>>>(pclA, F32(10), I32(15), SL256, N, 256);
    k_corr_mfma<<<FK * HDIM / 64, 256, 0, stream>>>(SL256, pclB, (const float*)nullptr,
                                                    I32(24), I32(25), pw_cc20, F32(41),
                                                    pw_cc21, F32(43), h1b, N, 256, 0);
    k_mfma_gemm<<<dim3(64, 4), 256, 0, stream>>>(h1b, nullptr, pw_c2o, F32(45),
                                                 nullptr, ab256, 480, 1, 256, N, 1);
    k_mfma_gemm<<<dim3(64, 4), 256, 0, stream>>>(ab256, nullptr, pw_c2o1, F32(47),
                                                 t512f, nullptr, 256, 1, 256, N, 0);
    k_slice<<<dim3(2048, 4), 256, 0, stream>>>(t512f, F32(12), I32(17), corr2T, N, 256, 256, 0);

    // --- Stage C: level-1 embed + blur + slices (per stream) ---
    auto stageC = [&](const float* el, const float* feat, const int* nbrs,
                      __hip_bfloat16* cat1, const float* baryO, const int* offO,
                      float* pclOut) {
        k_copy_el<<<32, 256, 0, stream>>>(el, cat1, N, 544);
        k_embed<<<128, 256, 0, stream>>>(feat, F32(30), F32(31), cat1, N, 256, 544, 260);
        k_mfma_gemm<<<dim3(64, 8), 256, 0, stream>>>(cat1, nbrs, pw_up1, F32(37),
                                                     nullptr, ab512, 544, 15, 512, N, 1);
        k_mfma_gemm<<<dim3(64, 8), 256, 0, stream>>>(ab512, nullptr, pw_up1_1, F32(39),
                                                     t512f, nullptr, 512, 1, 512, N, 0);
        k_slice<<<dim3(2048, 8), 256, 0, stream>>>(t512f, baryO, offO, pclOut, N, 512, 512, 0);
    };
    stageC(F32(8), F32(0), I32(22), catb1a, F32(12), I32(17), pcl01);
    stageC(F32(9), F32(3), I32(23), catb1b, F32(13), I32(18), pcl11);

    // --- Stage D: corr1 ---
    hipMemsetAsync(SL512, 0, (size_t)N * 512 * 4, stream);
    k_splat<<<dim3(2048, 8), 256, 0, stream>>>(pcl01, F32(12), I32(17), SL512, N, 512);
    hipMemsetAsync(SP256, 0, (size_t)N * 256 * 4, stream);
    k_splat<<<dim3(2048, 4), 256, 0, stream>>>(corr2T, F32(12), I32(17), SP256, N, 256);
    k_corr_mfma<<<FK * HDIM / 64, 256, 0, stream>>>(SL512, pcl11, SP256,
                                                    I32(26), I32(27), pw_cc10, F32(49),
                                                    pw_cc11, F32(51), h1b, N, 512, 256);
    k_mfma_gemm<<<dim3(64, 8), 256, 0, stream>>>(h1b, nullptr, pw_c1o, F32(53),
                                                 nullptr, ab512, 480, 1, 512, N, 1);
    k_mfma_gemm<<<dim3(64, 8), 256, 0, stream>>>(ab512, nullptr, pw_c1o1, F32(55),
                                                 t512f, nullptr, 512, 1, 512, N, 0);
    k_slice_b<<<dim3(2048, 8), 256, 0, stream>>>(t512f, F32(14), I32(19), corr1b, N, 512, 512, 0);

    // --- Stage E: head ---
    k_mfma_gemm<<<dim3(64, 8), 256, 0, stream>>>(corr1b, nullptr, pw_s4, F32(57),
                                                 nullptr, ab512, 512, 1, 512, N, 1);
    k_mfma_gemm<<<dim3(64, 4), 256, 0, stream>>>(ab512, nullptr, pw_s2, F32(59),
                                                 t512f, nullptr, 512, 1, 256, N, 1);
    k_final<<<32, 256, 0, stream>>>(t512f, F32(60), F32(61), (float*)d_out, N);
}